// Round 14
// baseline (304.705 us; speedup 1.0000x reference)
//
#include <hip/hip_runtime.h>
#include <math.h>

#define NNODES 20000
#define XP_COLS 65

typedef unsigned int uint32;
typedef __attribute__((ext_vector_type(8))) short short8;
typedef __attribute__((ext_vector_type(4))) float float4v;

__device__ __forceinline__ float bflo(uint32 u){ return __uint_as_float(u << 16); }
__device__ __forceinline__ float bfhi(uint32 u){ return __uint_as_float(u & 0xffff0000u); }
__device__ __forceinline__ unsigned short f2bf(float f){
  uint32 u = __float_as_uint(f);
  uint32 r = (u + 0x7fffu + ((u >> 16) & 1u)) >> 16;
  return (unsigned short)r;
}
__device__ __forceinline__ void unpack8(uint4 u, float* x){
  x[0]=bflo(u.x); x[1]=bfhi(u.x); x[2]=bflo(u.y); x[3]=bfhi(u.y);
  x[4]=bflo(u.z); x[5]=bfhi(u.z); x[6]=bflo(u.w); x[7]=bfhi(u.w);
}
// packed float2 helpers -> v_pk_* on gfx950
__device__ __forceinline__ float2 add2(float2 a, float2 b){ return make_float2(a.x + b.x, a.y + b.y); }
__device__ __forceinline__ float2 abs2(float2 a){ return make_float2(fmaxf(a.x, -a.x), fmaxf(a.y, -a.y)); }
__device__ __forceinline__ float2 fma2(float2 a, float2 b, float2 c){
  return make_float2(fmaf(a.x, b.x, c.x), fmaf(a.y, b.y, c.y));
}
__device__ __forceinline__ float2 fma2s(float s, float2 b, float2 c){
  return make_float2(fmaf(s, b.x, c.x), fmaf(s, b.y, c.y));
}
// sum across each 16-lane row via DPP row_ror (VALU-only, no LDS pipe)
__device__ __forceinline__ float rowsum16(float x){
  x += __int_as_float(__builtin_amdgcn_update_dpp(0, __float_as_int(x), 0x121, 0xf, 0xf, true));
  x += __int_as_float(__builtin_amdgcn_update_dpp(0, __float_as_int(x), 0x122, 0xf, 0xf, true));
  x += __int_as_float(__builtin_amdgcn_update_dpp(0, __float_as_int(x), 0x124, 0xf, 0xf, true));
  x += __int_as_float(__builtin_amdgcn_update_dpp(0, __float_as_int(x), 0x128, 0xf, 0xf, true));
  return x;
}
__device__ __forceinline__ float red64(float p){
  p = rowsum16(p);
  p += __shfl_xor(p, 16);
  p += __shfl_xor(p, 32);
  return p;
}

// ---------------- fused: edge-degree count + weight transpose/cast ----------------
__global__ void k_cvt_count(const int* __restrict__ dst, int E, int* __restrict__ deg,
                            const float* __restrict__ W1l, const float* __restrict__ W1r,
                            const float* __restrict__ W2l, const float* __restrict__ W2r,
                            const float* __restrict__ projW,
                            unsigned short* __restrict__ T1l, unsigned short* __restrict__ T1r,
                            unsigned short* __restrict__ T2l, unsigned short* __restrict__ T2r,
                            unsigned short* __restrict__ Tp){
  int gid = blockIdx.x * 256 + threadIdx.x;
  if (gid < E){
    atomicAdd(&deg[dst[gid]], 1);
    return;
  }
  int idx = gid - E;
  if (idx < 65536){
    int o = idx;
    int n = o >> 7, k = o & 127;
    T1l[o] = f2bf(W1l[k * 512 + n]);
  } else if (idx < 131072){
    int o = idx - 65536;
    int n = o >> 7, k = o & 127;
    T1r[o] = f2bf(W1r[k * 512 + n]);
  } else if (idx < 196608){
    int o = idx - 131072;
    int n = o >> 9, k = o & 511;
    T2l[o] = f2bf(W2l[k * 128 + n]);
  } else if (idx < 262144){
    int o = idx - 196608;
    int n = o >> 9, k = o & 511;
    T2r[o] = f2bf(W2r[k * 128 + n]);
  } else if (idx < 286720){
    int o = idx - 262144;
    int n = o / 192, k = o - n * 192;
    Tp[o] = f2bf(projW[k * 128 + n]);
  }
}

// chunked scan, int4-vectorized; deg[i]+1 accounts for self loop (deg pre-memset to 0)
__global__ __launch_bounds__(256) void k_scan(const int* __restrict__ deg,
                                              int* __restrict__ off,
                                              int* __restrict__ cursor){
  const int CH = 80;
  int tid = threadIdx.x;
  int lane = tid & 63, w = tid >> 6;
  int beg = tid * CH;
  bool act = beg < NNODES;
  int sum = 0;
  if (act){
    const int4* p = (const int4*)(deg + beg);
    #pragma unroll
    for (int i = 0; i < 20; i++){
      int4 v = p[i];
      sum += v.x + v.y + v.z + v.w + 4;
    }
  }
  int inc = sum;
  #pragma unroll
  for (int d = 1; d < 64; d <<= 1){
    int t = __shfl_up(inc, d, 64);
    if (lane >= d) inc += t;
  }
  __shared__ int wtot[4];
  if (lane == 63) wtot[w] = inc;
  __syncthreads();
  int wbase = 0;
  for (int i = 0; i < w; i++) wbase += wtot[i];
  int run = wbase + inc - sum;
  if (act){
    const int4* p = (const int4*)(deg + beg);
    int4* po = (int4*)(off + beg);
    int4* pc = (int4*)(cursor + beg);
    #pragma unroll
    for (int i = 0; i < 20; i++){
      int4 v = p[i];
      int4 o;
      o.x = run; run += v.x + 1;
      o.y = run; run += v.y + 1;
      o.z = run; run += v.z + 1;
      o.w = run; run += v.w + 1;
      po[i] = o; pc[i] = o;
    }
  }
  if (tid == 249) off[NNODES] = run;
}

__global__ void k_fill(const int* __restrict__ src, const int* __restrict__ dst, int E,
                       int* __restrict__ cursor, int* __restrict__ csr){
  int t = blockIdx.x * 256 + threadIdx.x;
  if (t < NNODES){
    int p = atomicAdd(&cursor[t], 1);
    csr[p] = t;
  } else if (t < NNODES + E){
    int e = t - NNODES;
    int p = atomicAdd(&cursor[dst[e]], 1);
    csr[p] = src[e];
  }
}

// ---------------- proj via MFMA with fused gather ----------------
__global__ __launch_bounds__(256) void k_proj_mfma(const float* __restrict__ xp,
                                                   const float* __restrict__ emb,
                                                   const unsigned short* __restrict__ Bt,
                                                   const float* __restrict__ bias,
                                                   unsigned short* __restrict__ Xb){
  __shared__ unsigned short As[64][40];
  __shared__ unsigned short Bs[128][40];
  __shared__ int ids[64];
  int tid = threadIdx.x;
  int bm = blockIdx.x * 64;
  int w = tid >> 6, lane = tid & 63;
  int wm = (w >> 1) * 32, wn = (w & 1) * 64;
  int quad = lane >> 4, l16 = lane & 15;
  if (tid < 64){
    int g = bm + tid;
    ids[tid] = (g < NNODES) ? (int)xp[(size_t)g * XP_COLS] : 0;
  }
  float4v acc[2][4];
  #pragma unroll
  for (int i = 0; i < 2; i++)
    #pragma unroll
    for (int j = 0; j < 4; j++) acc[i][j] = (float4v){0.f,0.f,0.f,0.f};
  int am = tid >> 2, ak = (tid & 3) * 8;
  int gm = bm + am;
  bool mv = gm < NNODES;
  int brow = tid >> 1, bk = (tid & 1) * 16;
  __syncthreads();

  for (int k0 = 0; k0 < 192; k0 += 32){
    float v[8];
    if (k0 < 128){
      const float* ep = emb + (size_t)ids[am] * 128 + k0 + ak;
      float4 e0 = *(const float4*)ep;
      float4 e1 = *(const float4*)(ep + 4);
      v[0]=e0.x; v[1]=e0.y; v[2]=e0.z; v[3]=e0.w;
      v[4]=e1.x; v[5]=e1.y; v[6]=e1.z; v[7]=e1.w;
    } else {
      const float* fp = xp + (size_t)gm * XP_COLS + 1 + (k0 - 128) + ak;
      #pragma unroll
      for (int i = 0; i < 8; i++) v[i] = mv ? fp[i] : 0.f;
    }
    ushort4 o0, o1;
    o0.x=f2bf(v[0]); o0.y=f2bf(v[1]); o0.z=f2bf(v[2]); o0.w=f2bf(v[3]);
    o1.x=f2bf(v[4]); o1.y=f2bf(v[5]); o1.z=f2bf(v[6]); o1.w=f2bf(v[7]);
    *(ushort4*)&As[am][ak]     = o0;
    *(ushort4*)&As[am][ak + 4] = o1;
    const unsigned short* bp = Bt + (size_t)brow * 192 + k0 + bk;
    *(uint4*)&Bs[brow][bk]     = *(const uint4*)bp;
    *(uint4*)&Bs[brow][bk + 8] = *(const uint4*)(bp + 8);
    __syncthreads();
    short8 af[2], bf[4];
    #pragma unroll
    for (int t = 0; t < 2; t++) af[t] = *(const short8*)&As[wm + t * 16 + l16][quad * 8];
    #pragma unroll
    for (int t = 0; t < 4; t++) bf[t] = *(const short8*)&Bs[wn + t * 16 + l16][quad * 8];
    #pragma unroll
    for (int tm = 0; tm < 2; tm++)
      #pragma unroll
      for (int tn = 0; tn < 4; tn++)
        acc[tm][tn] = __builtin_amdgcn_mfma_f32_16x16x32_bf16(af[tm], bf[tn], acc[tm][tn], 0, 0, 0);
    __syncthreads();
  }
  #pragma unroll
  for (int tm = 0; tm < 2; tm++){
    #pragma unroll
    for (int r = 0; r < 4; r++){
      int row = bm + wm + tm * 16 + quad * 4 + r;
      if (row >= NNODES) continue;
      #pragma unroll
      for (int tn = 0; tn < 4; tn++){
        int col = wn + tn * 16 + l16;
        float val = fmaxf(acc[tm][tn][r] + bias[col], 0.f);
        Xb[(size_t)row * 128 + col] = f2bf(val);
      }
    }
  }
}

// ---------------- MFMA GEMM with fused per-row attention dot + abs-dot bound ----------------
template<int K, int N, int MODE, int NH>
__global__ __launch_bounds__(256) void k_mfma(const unsigned short* __restrict__ A,
                                              const unsigned short* __restrict__ B0t,
                                              const unsigned short* __restrict__ B1t,
                                              void* __restrict__ C0, void* __restrict__ C1,
                                              const float* __restrict__ att,
                                              float* __restrict__ dl, float* __restrict__ dr,
                                              int* __restrict__ gmax){
  const unsigned short* Bt = blockIdx.z ? B1t : B0t;
  __shared__ unsigned short As[64][40];
  __shared__ unsigned short Bs[128][40];
  __shared__ float red[4][32];
  __shared__ float redu[4][32];
  int tid = threadIdx.x;
  int bm = blockIdx.y * 64;
  int bn = blockIdx.x * 128;
  int head = (NH == 1) ? 0 : blockIdx.x;
  int w = tid >> 6, lane = tid & 63;
  int wm = (w >> 1) * 32, wn = (w & 1) * 64;
  int quad = lane >> 4, l16 = lane & 15;
  float av[4], aav[4];
  #pragma unroll
  for (int tn = 0; tn < 4; tn++){
    av[tn] = att[head * 128 + wn + tn * 16 + l16];
    aav[tn] = fabsf(av[tn]);
  }
  float4v acc[2][4];
  #pragma unroll
  for (int i = 0; i < 2; i++)
    #pragma unroll
    for (int j = 0; j < 4; j++) acc[i][j] = (float4v){0.f,0.f,0.f,0.f};
  int am = tid >> 2, ak = (tid & 3) * 8;
  int gm = bm + am;
  bool mv = gm < NNODES;
  int brow = tid >> 1, bk = (tid & 1) * 16;

  for (int k0 = 0; k0 < K; k0 += 32){
    uint4 va = {0u,0u,0u,0u};
    if (mv) va = *(const uint4*)(A + (size_t)gm * K + k0 + ak);
    *(uint4*)&As[am][ak] = va;
    const unsigned short* bp = Bt + (size_t)(bn + brow) * K + k0 + bk;
    *(uint4*)&Bs[brow][bk]     = *(const uint4*)bp;
    *(uint4*)&Bs[brow][bk + 8] = *(const uint4*)(bp + 8);
    __syncthreads();
    short8 af[2], bf[4];
    #pragma unroll
    for (int t = 0; t < 2; t++) af[t] = *(const short8*)&As[wm + t * 16 + l16][quad * 8];
    #pragma unroll
    for (int t = 0; t < 4; t++) bf[t] = *(const short8*)&Bs[wn + t * 16 + l16][quad * 8];
    #pragma unroll
    for (int tm = 0; tm < 2; tm++)
      #pragma unroll
      for (int tn = 0; tn < 4; tn++)
        acc[tm][tn] = __builtin_amdgcn_mfma_f32_16x16x32_bf16(af[tm], bf[tn], acc[tm][tn], 0, 0, 0);
    __syncthreads();
  }
  #pragma unroll
  for (int tm = 0; tm < 2; tm++){
    #pragma unroll
    for (int r = 0; r < 4; r++){
      int row = bm + wm + tm * 16 + quad * 4 + r;
      if (row < NNODES){
        #pragma unroll
        for (int tn = 0; tn < 4; tn++){
          int col = bn + wn + tn * 16 + l16;
          float val = acc[tm][tn][r];
          if (MODE == 0 || blockIdx.z == 0){
            unsigned short* C = (unsigned short*)(blockIdx.z ? C1 : C0);
            C[(size_t)row * N + col] = f2bf(val);
          } else {
            ((float*)C1)[(size_t)row * N + col] = val;
          }
        }
      }
      float pd = acc[tm][0][r] * av[0];
      pd = fmaf(acc[tm][1][r], av[1], pd);
      pd = fmaf(acc[tm][2][r], av[2], pd);
      pd = fmaf(acc[tm][3][r], av[3], pd);
      float pu = fabsf(acc[tm][0][r]) * aav[0];
      pu = fmaf(fabsf(acc[tm][1][r]), aav[1], pu);
      pu = fmaf(fabsf(acc[tm][2][r]), aav[2], pu);
      pu = fmaf(fabsf(acc[tm][3][r]), aav[3], pu);
      pd = rowsum16(pd);
      pu = rowsum16(pu);
      if (l16 == 0){
        red[w][tm * 16 + quad * 4 + r]  = pd;
        redu[w][tm * 16 + quad * 4 + r] = pu;
      }
    }
  }
  __syncthreads();
  if (tid < 64){
    float vd, vu;
    if (tid < 32){ vd = red[0][tid] + red[1][tid];   vu = redu[0][tid] + redu[1][tid]; }
    else { vd = red[2][tid & 31] + red[3][tid & 31]; vu = redu[2][tid & 31] + redu[3][tid & 31]; }
    int row = bm + tid;
    bool ok = row < NNODES;
    if (ok){
      float* D = blockIdx.z ? dr : dl;
      D[row * NH + head] = vd;
    }
    if (blockIdx.z == 0){
      float v = ok ? fmaf(0.4f, vu, 0.6f * vd) : -4.0e6f;
      #pragma unroll
      for (int dd = 1; dd < 64; dd <<= 1) v = fmaxf(v, __shfl_xor(v, dd));
      if (tid == 0) atomicMax(&gmax[head], (int)ceilf(v * 256.0f) + (1 << 30));
    }
  }
}

// ---------------- layer-1 GATv2: block per node, round-robin unmasked batches, packed fp32 ----------------
__global__ __launch_bounds__(256) void k_attn1(const unsigned short* __restrict__ xl,
                                               const unsigned short* __restrict__ xr,
                                               const float* __restrict__ dl, const float* __restrict__ dr,
                                               const float* __restrict__ att, const float* __restrict__ bias,
                                               const int* __restrict__ gmax,
                                               const int* __restrict__ off, const int* __restrict__ csr,
                                               unsigned short* __restrict__ out){
  int tid = threadIdx.x;
  int w = tid >> 6, lane = tid & 63;
  int n = blockIdx.x;
  int h = lane >> 4;
  uint4 ur = *(const uint4*)(xr + (size_t)n * 512 + lane * 8);
  float2 r2[4] = { make_float2(bflo(ur.x), bfhi(ur.x)), make_float2(bflo(ur.y), bfhi(ur.y)),
                   make_float2(bflo(ur.z), bfhi(ur.z)), make_float2(bflo(ur.w), bfhi(ur.w)) };
  const float* ap = att + lane * 8;
  float4 A0 = *(const float4*)ap, A1 = *(const float4*)(ap + 4);
  float2 a2[4] = { make_float2(A0.x, A0.y), make_float2(A0.z, A0.w),
                   make_float2(A1.x, A1.y), make_float2(A1.z, A1.w) };
  float V = 0.f;
  #pragma unroll
  for (int i = 0; i < 4; i++){
    V = fmaf(fabsf(a2[i].x), fabsf(r2[i].x), V);
    V = fmaf(fabsf(a2[i].y), fabsf(r2[i].y), V);
  }
  V = rowsum16(V);
  float Mg = (float)(gmax[h] - (1 << 30)) * (1.0f / 256.0f);
  float base = fmaf(0.6f, dr[n * 4 + h], -Mg - 0.4f * V);
  int beg = off[n], end = off[n + 1];
  int cnt = end - beg;
  int Bf = cnt >> 2;                 // full unmasked 4-edge batches

  float s = 0.f;
  float2 acc2[4] = {make_float2(0.f,0.f), make_float2(0.f,0.f),
                    make_float2(0.f,0.f), make_float2(0.f,0.f)};
  for (int b = w; b < Bf; b += 4){
    int j0 = beg + b * 4;
    int s0 = csr[j0], s1 = csr[j0+1], s2 = csr[j0+2], s3 = csr[j0+3];
    uint4 u0 = *(const uint4*)(xl + (size_t)s0 * 512 + lane * 8);
    uint4 u1 = *(const uint4*)(xl + (size_t)s1 * 512 + lane * 8);
    uint4 u2 = *(const uint4*)(xl + (size_t)s2 * 512 + lane * 8);
    uint4 u3 = *(const uint4*)(xl + (size_t)s3 * 512 + lane * 8);
    float d0 = dl[s0 * 4 + h], d1 = dl[s1 * 4 + h];
    float d2 = dl[s2 * 4 + h], d3 = dl[s3 * 4 + h];
    float2 x0[4] = { make_float2(bflo(u0.x), bfhi(u0.x)), make_float2(bflo(u0.y), bfhi(u0.y)),
                     make_float2(bflo(u0.z), bfhi(u0.z)), make_float2(bflo(u0.w), bfhi(u0.w)) };
    float2 x1[4] = { make_float2(bflo(u1.x), bfhi(u1.x)), make_float2(bflo(u1.y), bfhi(u1.y)),
                     make_float2(bflo(u1.z), bfhi(u1.z)), make_float2(bflo(u1.w), bfhi(u1.w)) };
    float2 x2[4] = { make_float2(bflo(u2.x), bfhi(u2.x)), make_float2(bflo(u2.y), bfhi(u2.y)),
                     make_float2(bflo(u2.z), bfhi(u2.z)), make_float2(bflo(u2.w), bfhi(u2.w)) };
    float2 x3[4] = { make_float2(bflo(u3.x), bfhi(u3.x)), make_float2(bflo(u3.y), bfhi(u3.y)),
                     make_float2(bflo(u3.z), bfhi(u3.z)), make_float2(bflo(u3.w), bfhi(u3.w)) };
    float2 q0 = make_float2(0.f,0.f), q1 = make_float2(0.f,0.f);
    float2 q2 = make_float2(0.f,0.f), q3 = make_float2(0.f,0.f);
    #pragma unroll
    for (int i = 0; i < 4; i++){
      q0 = fma2(a2[i], abs2(add2(x0[i], r2[i])), q0);
      q1 = fma2(a2[i], abs2(add2(x1[i], r2[i])), q1);
      q2 = fma2(a2[i], abs2(add2(x2[i], r2[i])), q2);
      q3 = fma2(a2[i], abs2(add2(x3[i], r2[i])), q3);
    }
    float p0 = q0.x + q0.y, p1 = q1.x + q1.y, p2 = q2.x + q2.y, p3 = q3.x + q3.y;
    p0 = rowsum16(p0); p1 = rowsum16(p1); p2 = rowsum16(p2); p3 = rowsum16(p3);
    float ex0 = __expf(fmaf(0.4f, p0, fmaf(0.6f, d0, base)));
    float ex1 = __expf(fmaf(0.4f, p1, fmaf(0.6f, d1, base)));
    float ex2 = __expf(fmaf(0.4f, p2, fmaf(0.6f, d2, base)));
    float ex3 = __expf(fmaf(0.4f, p3, fmaf(0.6f, d3, base)));
    s += (ex0 + ex1) + (ex2 + ex3);
    #pragma unroll
    for (int i = 0; i < 4; i++){
      float2 t = fma2s(ex0, x0[i], acc2[i]);
      t = fma2s(ex1, x1[i], t);
      t = fma2s(ex2, x2[i], t);
      acc2[i] = fma2s(ex3, x3[i], t);
    }
  }
  // remainder (<=3 edges) handled by the wave that owns batch index Bf in round-robin
  if ((cnt & 3) && w == (Bf & 3)){
    for (int j = beg + Bf * 4; j < end; j++){
      int sn = csr[j];
      float dls = dl[sn * 4 + h];
      uint4 ux = *(const uint4*)(xl + (size_t)sn * 512 + lane * 8);
      float2 x[4] = { make_float2(bflo(ux.x), bfhi(ux.x)), make_float2(bflo(ux.y), bfhi(ux.y)),
                      make_float2(bflo(ux.z), bfhi(ux.z)), make_float2(bflo(ux.w), bfhi(ux.w)) };
      float2 q = make_float2(0.f,0.f);
      #pragma unroll
      for (int i = 0; i < 4; i++) q = fma2(a2[i], abs2(add2(x[i], r2[i])), q);
      float p = rowsum16(q.x + q.y);
      float ex = __expf(fmaf(0.4f, p, fmaf(0.6f, dls, base)));
      s += ex;
      #pragma unroll
      for (int i = 0; i < 4; i++) acc2[i] = fma2s(ex, x[i], acc2[i]);
    }
  }
  __shared__ float accsh[4][512];
  __shared__ float ssh[4][4];
  *(float4*)&accsh[w][lane * 8]     = make_float4(acc2[0].x, acc2[0].y, acc2[1].x, acc2[1].y);
  *(float4*)&accsh[w][lane * 8 + 4] = make_float4(acc2[2].x, acc2[2].y, acc2[3].x, acc2[3].y);
  if ((lane & 15) == 0) ssh[w][h] = s;
  __syncthreads();
  for (int c = tid; c < 512; c += 256){
    float v = (accsh[0][c] + accsh[1][c]) + (accsh[2][c] + accsh[3][c]);
    int hh = c >> 7;
    float sv = (ssh[0][hh] + ssh[1][hh]) + (ssh[2][hh] + ssh[3][hh]);
    float o = v / (sv + 1e-16f) + bias[c];
    out[(size_t)n * 512 + c] = f2bf(fmaxf(o, 0.f));
  }
}

// ---------------- layer-2 GATv2 + fused output GEMM: block per node, unmasked batches, packed ----------------
__global__ __launch_bounds__(256) void k_attn2(const unsigned short* __restrict__ xl,
                                               const float* __restrict__ xr,
                                               const float* __restrict__ dl, const float* __restrict__ dr,
                                               const float* __restrict__ att, const float* __restrict__ bias,
                                               const float* __restrict__ outW, const float* __restrict__ outb,
                                               const int* __restrict__ gmax,
                                               const int* __restrict__ off, const int* __restrict__ csr,
                                               float* __restrict__ out){
  __shared__ float accsh[4][128];
  __shared__ float ssh[4];
  __shared__ float x2sh[128];
  int tid = threadIdx.x;
  int w = tid >> 6, lane = tid & 63;
  int n = blockIdx.x;
  // wave 0: preload the 20 outW values this lane needs (rows c, c+1 of [128][10])
  float Wr[20];
  if (w == 0){
    const float* wp = outW + lane * 20;
    #pragma unroll
    for (int i = 0; i < 5; i++){
      float4 v = *(const float4*)(wp + i * 4);
      Wr[i*4] = v.x; Wr[i*4+1] = v.y; Wr[i*4+2] = v.z; Wr[i*4+3] = v.w;
    }
  }
  float2 rv = *(const float2*)(xr + (size_t)n * 128 + lane * 2);
  float2 av = *(const float2*)(att + lane * 2);
  float V = red64(fmaf(fabsf(av.x), fabsf(rv.x), fabsf(av.y) * fabsf(rv.y)));
  float Mg = (float)(gmax[0] - (1 << 30)) * (1.0f / 256.0f);
  float base = fmaf(0.6f, dr[n], -Mg - 0.4f * V);
  int beg = off[n], end = off[n + 1];
  int cnt = end - beg;
  int Bf = cnt >> 2;
  float s = 0.f;
  float2 acc = make_float2(0.f, 0.f);
  for (int b = w; b < Bf; b += 4){
    int j0 = beg + b * 4;
    int s0 = csr[j0], s1 = csr[j0+1], s2 = csr[j0+2], s3 = csr[j0+3];
    uint32 u0 = *(const uint32*)(xl + (size_t)s0 * 128 + lane * 2);
    uint32 u1 = *(const uint32*)(xl + (size_t)s1 * 128 + lane * 2);
    uint32 u2 = *(const uint32*)(xl + (size_t)s2 * 128 + lane * 2);
    uint32 u3 = *(const uint32*)(xl + (size_t)s3 * 128 + lane * 2);
    float d0 = dl[s0], d1 = dl[s1], d2 = dl[s2], d3 = dl[s3];
    float2 x0 = make_float2(bflo(u0), bfhi(u0));
    float2 x1 = make_float2(bflo(u1), bfhi(u1));
    float2 x2 = make_float2(bflo(u2), bfhi(u2));
    float2 x3 = make_float2(bflo(u3), bfhi(u3));
    float2 q0 = fma2(av, abs2(add2(x0, rv)), make_float2(0.f,0.f));
    float2 q1 = fma2(av, abs2(add2(x1, rv)), make_float2(0.f,0.f));
    float2 q2 = fma2(av, abs2(add2(x2, rv)), make_float2(0.f,0.f));
    float2 q3 = fma2(av, abs2(add2(x3, rv)), make_float2(0.f,0.f));
    float p0 = red64(q0.x + q0.y);
    float p1 = red64(q1.x + q1.y);
    float p2 = red64(q2.x + q2.y);
    float p3 = red64(q3.x + q3.y);
    float ex0 = __expf(fmaf(0.4f, p0, fmaf(0.6f, d0, base)));
    float ex1 = __expf(fmaf(0.4f, p1, fmaf(0.6f, d1, base)));
    float ex2 = __expf(fmaf(0.4f, p2, fmaf(0.6f, d2, base)));
    float ex3 = __expf(fmaf(0.4f, p3, fmaf(0.6f, d3, base)));
    s += (ex0 + ex1) + (ex2 + ex3);
    float2 t = fma2s(ex0, x0, acc);
    t = fma2s(ex1, x1, t);
    t = fma2s(ex2, x2, t);
    acc = fma2s(ex3, x3, t);
  }
  if ((cnt & 3) && w == (Bf & 3)){
    for (int j = beg + Bf * 4; j < end; j++){
      int sn = csr[j];
      float dls = dl[sn];
      uint32 u = *(const uint32*)(xl + (size_t)sn * 128 + lane * 2);
      float2 x = make_float2(bflo(u), bfhi(u));
      float2 q = fma2(av, abs2(add2(x, rv)), make_float2(0.f,0.f));
      float p = red64(q.x + q.y);
      float ex = __expf(fmaf(0.4f, p, fmaf(0.6f, dls, base)));
      s += ex;
      acc = fma2s(ex, x, acc);
    }
  }
  accsh[w][lane * 2]     = acc.x;
  accsh[w][lane * 2 + 1] = acc.y;
  if (lane == 0) ssh[w] = s;
  __syncthreads();
  if (tid < 128){
    float v = (accsh[0][tid] + accsh[1][tid]) + (accsh[2][tid] + accsh[3][tid]);
    float sv = (ssh[0] + ssh[1]) + (ssh[2] + ssh[3]);
    x2sh[tid] = v / (sv + 1e-16f) + bias[tid];
  }
  __syncthreads();
  if (w == 0){
    int c = lane * 2;
    float x0 = x2sh[c], x1 = x2sh[c + 1];
    #pragma unroll
    for (int o = 0; o < 10; o++){
      float p = fmaf(x0, Wr[o], x1 * Wr[10 + o]);
      p = red64(p);
      if (lane == 0) out[(size_t)n * 10 + o] = p + outb[o];
    }
  }
}

extern "C" void kernel_launch(void* const* d_in, const int* in_sizes, int n_in,
                              void* d_out, int out_size, void* d_ws, size_t ws_size,
                              hipStream_t stream){
  const float* xp    = (const float*)d_in[0];
  const int*   ei    = (const int*)  d_in[1];
  const float* emb   = (const float*)d_in[2];
  const float* projW = (const float*)d_in[3];
  const float* projb = (const float*)d_in[4];
  const float* W1l   = (const float*)d_in[5];
  const float* W1r   = (const float*)d_in[6];
  const float* att1  = (const float*)d_in[7];
  const float* b1    = (const float*)d_in[8];
  const float* W2l   = (const float*)d_in[9];
  const float* W2r   = (const float*)d_in[10];
  const float* att2  = (const float*)d_in[11];
  const float* b2    = (const float*)d_in[12];
  const float* outW  = (const float*)d_in[13];
  const float* outb  = (const float*)d_in[14];
  float* out = (float*)d_out;

  int E = in_sizes[1] / 2;
  const int* esrc = ei;
  const int* edst = ei + E;

  char* w = (char*)d_ws;
  int* gmaxi = (int*)w; w += 32;            // [0..3] layer1 heads, [4] layer2
  int* deg  = (int*)w; w += (size_t)NNODES * 4;
  int* off  = (int*)w; w += (size_t)(NNODES + 4) * 4;
  int* cur  = (int*)w; w += (size_t)NNODES * 4;
  int* csr  = (int*)w; w += (size_t)(NNODES + E) * 4;
  unsigned short* Xb   = (unsigned short*)w; w += (size_t)NNODES * 128 * 2;
  unsigned short* Wt1l = (unsigned short*)w; w += (size_t)512 * 128 * 2;
  unsigned short* Wt1r = (unsigned short*)w; w += (size_t)512 * 128 * 2;
  unsigned short* Wt2l = (unsigned short*)w; w += (size_t)128 * 512 * 2;
  unsigned short* Wt2r = (unsigned short*)w; w += (size_t)128 * 512 * 2;
  unsigned short* Wtp  = (unsigned short*)w; w += (size_t)128 * 192 * 2;
  unsigned short* xl1b = (unsigned short*)w; w += (size_t)NNODES * 512 * 2;
  unsigned short* xr1b = (unsigned short*)w; w += (size_t)NNODES * 512 * 2;
  unsigned short* X1b  = (unsigned short*)w; w += (size_t)NNODES * 512 * 2;
  unsigned short* xl2b = (unsigned short*)w; w += (size_t)NNODES * 128 * 2;
  float* xr2 = (float*)w; w += (size_t)NNODES * 128 * 4;
  float* dl1 = (float*)w; w += (size_t)NNODES * 4 * 4;
  float* dr1 = (float*)w; w += (size_t)NNODES * 4 * 4;
  float* dl2 = (float*)w; w += (size_t)NNODES * 4;
  float* dr2 = (float*)w; w += (size_t)NNODES * 4;

  hipMemsetAsync(gmaxi, 0, 32 + (size_t)NNODES * 4, stream);  // covers gmaxi + deg
  int cvt_total = E + 286720;
  k_cvt_count<<<(cvt_total + 255) / 256, 256, 0, stream>>>(
      edst, E, deg, W1l, W1r, W2l, W2r, projW, Wt1l, Wt1r, Wt2l, Wt2r, Wtp);
  k_scan<<<1, 256, 0, stream>>>(deg, off, cur);
  k_fill<<<(NNODES + E + 255) / 256, 256, 0, stream>>>(esrc, edst, E, cur, csr);

  k_proj_mfma<<<dim3((NNODES + 63) / 64), 256, 0, stream>>>(xp, emb, Wtp, projb, Xb);
  k_mfma<128, 512, 0, 4><<<dim3(4, (NNODES + 63) / 64, 2), 256, 0, stream>>>(
      Xb, Wt1l, Wt1r, xl1b, xr1b, att1, dl1, dr1, gmaxi);
  k_attn1<<<NNODES, 256, 0, stream>>>(xl1b, xr1b, dl1, dr1, att1, b1, gmaxi, off, csr, X1b);
  k_mfma<512, 128, 1, 1><<<dim3(1, (NNODES + 63) / 64, 2), 256, 0, stream>>>(
      X1b, Wt2l, Wt2r, xl2b, xr2, att2, dl2, dr2, gmaxi + 4);
  k_attn2<<<NNODES, 256, 0, stream>>>(xl2b, xr2, dl2, dr2, att2, b2, outW, outb, gmaxi + 4, off, csr, out);
}

// Round 15
// 286.782 us; speedup vs baseline: 1.0625x; 1.0625x over previous
//
#include <hip/hip_runtime.h>
#include <math.h>

#define NNODES 20000
#define XP_COLS 65

typedef unsigned int uint32;
typedef __attribute__((ext_vector_type(8))) short short8;
typedef __attribute__((ext_vector_type(4))) float float4v;

__device__ __forceinline__ float bflo(uint32 u){ return __uint_as_float(u << 16); }
__device__ __forceinline__ float bfhi(uint32 u){ return __uint_as_float(u & 0xffff0000u); }
__device__ __forceinline__ unsigned short f2bf(float f){
  uint32 u = __float_as_uint(f);
  uint32 r = (u + 0x7fffu + ((u >> 16) & 1u)) >> 16;
  return (unsigned short)r;
}
__device__ __forceinline__ void unpack8(uint4 u, float* x){
  x[0]=bflo(u.x); x[1]=bfhi(u.x); x[2]=bflo(u.y); x[3]=bfhi(u.y);
  x[4]=bflo(u.z); x[5]=bfhi(u.z); x[6]=bflo(u.w); x[7]=bfhi(u.w);
}
// sum across each 16-lane row via DPP row_ror (VALU-only, no LDS pipe)
__device__ __forceinline__ float rowsum16(float x){
  x += __int_as_float(__builtin_amdgcn_update_dpp(0, __float_as_int(x), 0x121, 0xf, 0xf, true));
  x += __int_as_float(__builtin_amdgcn_update_dpp(0, __float_as_int(x), 0x122, 0xf, 0xf, true));
  x += __int_as_float(__builtin_amdgcn_update_dpp(0, __float_as_int(x), 0x124, 0xf, 0xf, true));
  x += __int_as_float(__builtin_amdgcn_update_dpp(0, __float_as_int(x), 0x128, 0xf, 0xf, true));
  return x;
}
__device__ __forceinline__ float red64(float p){
  p = rowsum16(p);
  p += __shfl_xor(p, 16);
  p += __shfl_xor(p, 32);
  return p;
}

// ---------------- fused: edge-degree count + weight transpose/cast ----------------
__global__ void k_cvt_count(const int* __restrict__ dst, int E, int* __restrict__ deg,
                            const float* __restrict__ W1l, const float* __restrict__ W1r,
                            const float* __restrict__ W2l, const float* __restrict__ W2r,
                            const float* __restrict__ projW,
                            unsigned short* __restrict__ T1l, unsigned short* __restrict__ T1r,
                            unsigned short* __restrict__ T2l, unsigned short* __restrict__ T2r,
                            unsigned short* __restrict__ Tp){
  int gid = blockIdx.x * 256 + threadIdx.x;
  if (gid < E){
    atomicAdd(&deg[dst[gid]], 1);
    return;
  }
  int idx = gid - E;
  if (idx < 65536){
    int o = idx;
    int n = o >> 7, k = o & 127;
    T1l[o] = f2bf(W1l[k * 512 + n]);
  } else if (idx < 131072){
    int o = idx - 65536;
    int n = o >> 7, k = o & 127;
    T1r[o] = f2bf(W1r[k * 512 + n]);
  } else if (idx < 196608){
    int o = idx - 131072;
    int n = o >> 9, k = o & 511;
    T2l[o] = f2bf(W2l[k * 128 + n]);
  } else if (idx < 262144){
    int o = idx - 196608;
    int n = o >> 9, k = o & 511;
    T2r[o] = f2bf(W2r[k * 128 + n]);
  } else if (idx < 286720){
    int o = idx - 262144;
    int n = o / 192, k = o - n * 192;
    Tp[o] = f2bf(projW[k * 128 + n]);
  }
}

// chunked scan, int4-vectorized; deg[i]+1 accounts for self loop (deg pre-memset to 0)
__global__ __launch_bounds__(256) void k_scan(const int* __restrict__ deg,
                                              int* __restrict__ off,
                                              int* __restrict__ cursor){
  const int CH = 80;
  int tid = threadIdx.x;
  int lane = tid & 63, w = tid >> 6;
  int beg = tid * CH;
  bool act = beg < NNODES;
  int sum = 0;
  if (act){
    const int4* p = (const int4*)(deg + beg);
    #pragma unroll
    for (int i = 0; i < 20; i++){
      int4 v = p[i];
      sum += v.x + v.y + v.z + v.w + 4;
    }
  }
  int inc = sum;
  #pragma unroll
  for (int d = 1; d < 64; d <<= 1){
    int t = __shfl_up(inc, d, 64);
    if (lane >= d) inc += t;
  }
  __shared__ int wtot[4];
  if (lane == 63) wtot[w] = inc;
  __syncthreads();
  int wbase = 0;
  for (int i = 0; i < w; i++) wbase += wtot[i];
  int run = wbase + inc - sum;
  if (act){
    const int4* p = (const int4*)(deg + beg);
    int4* po = (int4*)(off + beg);
    int4* pc = (int4*)(cursor + beg);
    #pragma unroll
    for (int i = 0; i < 20; i++){
      int4 v = p[i];
      int4 o;
      o.x = run; run += v.x + 1;
      o.y = run; run += v.y + 1;
      o.z = run; run += v.z + 1;
      o.w = run; run += v.w + 1;
      po[i] = o; pc[i] = o;
    }
  }
  if (tid == 249) off[NNODES] = run;
}

__global__ void k_fill(const int* __restrict__ src, const int* __restrict__ dst, int E,
                       int* __restrict__ cursor, int* __restrict__ csr){
  int t = blockIdx.x * 256 + threadIdx.x;
  if (t < NNODES){
    int p = atomicAdd(&cursor[t], 1);
    csr[p] = t;
  } else if (t < NNODES + E){
    int e = t - NNODES;
    int p = atomicAdd(&cursor[dst[e]], 1);
    csr[p] = src[e];
  }
}

// ---------------- proj via MFMA with fused gather ----------------
__global__ __launch_bounds__(256) void k_proj_mfma(const float* __restrict__ xp,
                                                   const float* __restrict__ emb,
                                                   const unsigned short* __restrict__ Bt,
                                                   const float* __restrict__ bias,
                                                   unsigned short* __restrict__ Xb){
  __shared__ unsigned short As[64][40];
  __shared__ unsigned short Bs[128][40];
  __shared__ int ids[64];
  int tid = threadIdx.x;
  int bm = blockIdx.x * 64;
  int w = tid >> 6, lane = tid & 63;
  int wm = (w >> 1) * 32, wn = (w & 1) * 64;
  int quad = lane >> 4, l16 = lane & 15;
  if (tid < 64){
    int g = bm + tid;
    ids[tid] = (g < NNODES) ? (int)xp[(size_t)g * XP_COLS] : 0;
  }
  float4v acc[2][4];
  #pragma unroll
  for (int i = 0; i < 2; i++)
    #pragma unroll
    for (int j = 0; j < 4; j++) acc[i][j] = (float4v){0.f,0.f,0.f,0.f};
  int am = tid >> 2, ak = (tid & 3) * 8;
  int gm = bm + am;
  bool mv = gm < NNODES;
  int brow = tid >> 1, bk = (tid & 1) * 16;
  __syncthreads();

  for (int k0 = 0; k0 < 192; k0 += 32){
    float v[8];
    if (k0 < 128){
      const float* ep = emb + (size_t)ids[am] * 128 + k0 + ak;
      float4 e0 = *(const float4*)ep;
      float4 e1 = *(const float4*)(ep + 4);
      v[0]=e0.x; v[1]=e0.y; v[2]=e0.z; v[3]=e0.w;
      v[4]=e1.x; v[5]=e1.y; v[6]=e1.z; v[7]=e1.w;
    } else {
      const float* fp = xp + (size_t)gm * XP_COLS + 1 + (k0 - 128) + ak;
      #pragma unroll
      for (int i = 0; i < 8; i++) v[i] = mv ? fp[i] : 0.f;
    }
    ushort4 o0, o1;
    o0.x=f2bf(v[0]); o0.y=f2bf(v[1]); o0.z=f2bf(v[2]); o0.w=f2bf(v[3]);
    o1.x=f2bf(v[4]); o1.y=f2bf(v[5]); o1.z=f2bf(v[6]); o1.w=f2bf(v[7]);
    *(ushort4*)&As[am][ak]     = o0;
    *(ushort4*)&As[am][ak + 4] = o1;
    const unsigned short* bp = Bt + (size_t)brow * 192 + k0 + bk;
    *(uint4*)&Bs[brow][bk]     = *(const uint4*)bp;
    *(uint4*)&Bs[brow][bk + 8] = *(const uint4*)(bp + 8);
    __syncthreads();
    short8 af[2], bf[4];
    #pragma unroll
    for (int t = 0; t < 2; t++) af[t] = *(const short8*)&As[wm + t * 16 + l16][quad * 8];
    #pragma unroll
    for (int t = 0; t < 4; t++) bf[t] = *(const short8*)&Bs[wn + t * 16 + l16][quad * 8];
    #pragma unroll
    for (int tm = 0; tm < 2; tm++)
      #pragma unroll
      for (int tn = 0; tn < 4; tn++)
        acc[tm][tn] = __builtin_amdgcn_mfma_f32_16x16x32_bf16(af[tm], bf[tn], acc[tm][tn], 0, 0, 0);
    __syncthreads();
  }
  #pragma unroll
  for (int tm = 0; tm < 2; tm++){
    #pragma unroll
    for (int r = 0; r < 4; r++){
      int row = bm + wm + tm * 16 + quad * 4 + r;
      if (row >= NNODES) continue;
      #pragma unroll
      for (int tn = 0; tn < 4; tn++){
        int col = wn + tn * 16 + l16;
        float val = fmaxf(acc[tm][tn][r] + bias[col], 0.f);
        Xb[(size_t)row * 128 + col] = f2bf(val);
      }
    }
  }
}

// ---------------- MFMA GEMM with fused per-row attention dot + abs-dot bound ----------------
template<int K, int N, int MODE, int NH>
__global__ __launch_bounds__(256) void k_mfma(const unsigned short* __restrict__ A,
                                              const unsigned short* __restrict__ B0t,
                                              const unsigned short* __restrict__ B1t,
                                              void* __restrict__ C0, void* __restrict__ C1,
                                              const float* __restrict__ att,
                                              float* __restrict__ dl, float* __restrict__ dr,
                                              int* __restrict__ gmax){
  const unsigned short* Bt = blockIdx.z ? B1t : B0t;
  __shared__ unsigned short As[64][40];
  __shared__ unsigned short Bs[128][40];
  __shared__ float red[4][32];
  __shared__ float redu[4][32];
  int tid = threadIdx.x;
  int bm = blockIdx.y * 64;
  int bn = blockIdx.x * 128;
  int head = (NH == 1) ? 0 : blockIdx.x;
  int w = tid >> 6, lane = tid & 63;
  int wm = (w >> 1) * 32, wn = (w & 1) * 64;
  int quad = lane >> 4, l16 = lane & 15;
  float av[4], aav[4];
  #pragma unroll
  for (int tn = 0; tn < 4; tn++){
    av[tn] = att[head * 128 + wn + tn * 16 + l16];
    aav[tn] = fabsf(av[tn]);
  }
  float4v acc[2][4];
  #pragma unroll
  for (int i = 0; i < 2; i++)
    #pragma unroll
    for (int j = 0; j < 4; j++) acc[i][j] = (float4v){0.f,0.f,0.f,0.f};
  int am = tid >> 2, ak = (tid & 3) * 8;
  int gm = bm + am;
  bool mv = gm < NNODES;
  int brow = tid >> 1, bk = (tid & 1) * 16;

  for (int k0 = 0; k0 < K; k0 += 32){
    uint4 va = {0u,0u,0u,0u};
    if (mv) va = *(const uint4*)(A + (size_t)gm * K + k0 + ak);
    *(uint4*)&As[am][ak] = va;
    const unsigned short* bp = Bt + (size_t)(bn + brow) * K + k0 + bk;
    *(uint4*)&Bs[brow][bk]     = *(const uint4*)bp;
    *(uint4*)&Bs[brow][bk + 8] = *(const uint4*)(bp + 8);
    __syncthreads();
    short8 af[2], bf[4];
    #pragma unroll
    for (int t = 0; t < 2; t++) af[t] = *(const short8*)&As[wm + t * 16 + l16][quad * 8];
    #pragma unroll
    for (int t = 0; t < 4; t++) bf[t] = *(const short8*)&Bs[wn + t * 16 + l16][quad * 8];
    #pragma unroll
    for (int tm = 0; tm < 2; tm++)
      #pragma unroll
      for (int tn = 0; tn < 4; tn++)
        acc[tm][tn] = __builtin_amdgcn_mfma_f32_16x16x32_bf16(af[tm], bf[tn], acc[tm][tn], 0, 0, 0);
    __syncthreads();
  }
  #pragma unroll
  for (int tm = 0; tm < 2; tm++){
    #pragma unroll
    for (int r = 0; r < 4; r++){
      int row = bm + wm + tm * 16 + quad * 4 + r;
      if (row < NNODES){
        #pragma unroll
        for (int tn = 0; tn < 4; tn++){
          int col = bn + wn + tn * 16 + l16;
          float val = acc[tm][tn][r];
          if (MODE == 0 || blockIdx.z == 0){
            unsigned short* C = (unsigned short*)(blockIdx.z ? C1 : C0);
            C[(size_t)row * N + col] = f2bf(val);
          } else {
            ((float*)C1)[(size_t)row * N + col] = val;
          }
        }
      }
      float pd = acc[tm][0][r] * av[0];
      pd = fmaf(acc[tm][1][r], av[1], pd);
      pd = fmaf(acc[tm][2][r], av[2], pd);
      pd = fmaf(acc[tm][3][r], av[3], pd);
      float pu = fabsf(acc[tm][0][r]) * aav[0];
      pu = fmaf(fabsf(acc[tm][1][r]), aav[1], pu);
      pu = fmaf(fabsf(acc[tm][2][r]), aav[2], pu);
      pu = fmaf(fabsf(acc[tm][3][r]), aav[3], pu);
      pd = rowsum16(pd);
      pu = rowsum16(pu);
      if (l16 == 0){
        red[w][tm * 16 + quad * 4 + r]  = pd;
        redu[w][tm * 16 + quad * 4 + r] = pu;
      }
    }
  }
  __syncthreads();
  if (tid < 64){
    float vd, vu;
    if (tid < 32){ vd = red[0][tid] + red[1][tid];   vu = redu[0][tid] + redu[1][tid]; }
    else { vd = red[2][tid & 31] + red[3][tid & 31]; vu = redu[2][tid & 31] + redu[3][tid & 31]; }
    int row = bm + tid;
    bool ok = row < NNODES;
    if (ok){
      float* D = blockIdx.z ? dr : dl;
      D[row * NH + head] = vd;
    }
    if (blockIdx.z == 0){
      float v = ok ? fmaf(0.4f, vu, 0.6f * vd) : -4.0e6f;
      #pragma unroll
      for (int dd = 1; dd < 64; dd <<= 1) v = fmaxf(v, __shfl_xor(v, dd));
      if (tid == 0) atomicMax(&gmax[head], (int)ceilf(v * 256.0f) + (1 << 30));
    }
  }
}

// ---------------- layer-1 GATv2: block per node, round-robin 4-edge batches per wave (r13 best) ----------------
__global__ __launch_bounds__(256) void k_attn1(const unsigned short* __restrict__ xl,
                                               const unsigned short* __restrict__ xr,
                                               const float* __restrict__ dl, const float* __restrict__ dr,
                                               const float* __restrict__ att, const float* __restrict__ bias,
                                               const int* __restrict__ gmax,
                                               const int* __restrict__ off, const int* __restrict__ csr,
                                               unsigned short* __restrict__ out){
  int tid = threadIdx.x;
  int w = tid >> 6, lane = tid & 63;
  int n = blockIdx.x;
  int h = lane >> 4;
  uint4 ur = *(const uint4*)(xr + (size_t)n * 512 + lane * 8);
  float r[8]; unpack8(ur, r);
  const float* ap = att + lane * 8;
  float4 A0 = *(const float4*)ap, A1 = *(const float4*)(ap + 4);
  float a[8] = {A0.x,A0.y,A0.z,A0.w,A1.x,A1.y,A1.z,A1.w};
  float V = 0.f;
  #pragma unroll
  for (int i = 0; i < 8; i++) V = fmaf(fabsf(a[i]), fabsf(r[i]), V);
  V = rowsum16(V);
  float Mg = (float)(gmax[h] - (1 << 30)) * (1.0f / 256.0f);
  float base = fmaf(0.6f, dr[n * 4 + h], -Mg - 0.4f * V);
  int beg = off[n], end = off[n + 1];
  int cnt = end - beg;
  int B = (cnt + 3) >> 2;                 // 4-edge batches over whole list

  float s = 0.f;
  float acc[8] = {0,0,0,0,0,0,0,0};
  for (int b = w; b < B; b += 4){
    int j0 = beg + b * 4;
    int i1 = j0 + 1, i2 = j0 + 2, i3 = j0 + 3;
    float m1 = 1.f, m2 = 1.f, m3 = 1.f;
    if (i1 >= end){ i1 = j0; m1 = 0.f; }
    if (i2 >= end){ i2 = j0; m2 = 0.f; }
    if (i3 >= end){ i3 = j0; m3 = 0.f; }
    int s0 = csr[j0], s1 = csr[i1], s2 = csr[i2], s3 = csr[i3];
    uint4 u0 = *(const uint4*)(xl + (size_t)s0 * 512 + lane * 8);
    uint4 u1 = *(const uint4*)(xl + (size_t)s1 * 512 + lane * 8);
    uint4 u2 = *(const uint4*)(xl + (size_t)s2 * 512 + lane * 8);
    uint4 u3 = *(const uint4*)(xl + (size_t)s3 * 512 + lane * 8);
    float d0 = dl[s0 * 4 + h], d1 = dl[s1 * 4 + h];
    float d2 = dl[s2 * 4 + h], d3 = dl[s3 * 4 + h];
    float x0[8], x1[8], x2[8], x3[8];
    unpack8(u0, x0); unpack8(u1, x1); unpack8(u2, x2); unpack8(u3, x3);
    float p0 = 0.f, p1 = 0.f, p2 = 0.f, p3 = 0.f;
    #pragma unroll
    for (int i = 0; i < 8; i++){
      p0 = fmaf(a[i], fabsf(x0[i] + r[i]), p0);
      p1 = fmaf(a[i], fabsf(x1[i] + r[i]), p1);
      p2 = fmaf(a[i], fabsf(x2[i] + r[i]), p2);
      p3 = fmaf(a[i], fabsf(x3[i] + r[i]), p3);
    }
    p0 = rowsum16(p0); p1 = rowsum16(p1); p2 = rowsum16(p2); p3 = rowsum16(p3);
    float ex0 = __expf(fmaf(0.4f, p0, fmaf(0.6f, d0, base)));
    float ex1 = __expf(fmaf(0.4f, p1, fmaf(0.6f, d1, base))) * m1;
    float ex2 = __expf(fmaf(0.4f, p2, fmaf(0.6f, d2, base))) * m2;
    float ex3 = __expf(fmaf(0.4f, p3, fmaf(0.6f, d3, base))) * m3;
    s += (ex0 + ex1) + (ex2 + ex3);
    #pragma unroll
    for (int i = 0; i < 8; i++){
      float t = fmaf(ex0, x0[i], ex1 * x1[i]);
      t = fmaf(ex2, x2[i], t);
      acc[i] = fmaf(ex3, x3[i], acc[i] + t);
    }
  }
  __shared__ float accsh[4][512];
  __shared__ float ssh[4][4];
  *(float4*)&accsh[w][lane * 8]     = make_float4(acc[0], acc[1], acc[2], acc[3]);
  *(float4*)&accsh[w][lane * 8 + 4] = make_float4(acc[4], acc[5], acc[6], acc[7]);
  if ((lane & 15) == 0) ssh[w][h] = s;
  __syncthreads();
  for (int c = tid; c < 512; c += 256){
    float v = (accsh[0][c] + accsh[1][c]) + (accsh[2][c] + accsh[3][c]);
    int hh = c >> 7;
    float sv = (ssh[0][hh] + ssh[1][hh]) + (ssh[2][hh] + ssh[3][hh]);
    float o = v / (sv + 1e-16f) + bias[c];
    out[(size_t)n * 512 + c] = f2bf(fmaxf(o, 0.f));
  }
}

// ---------------- attn2 batch compute (4 edges, branch-free, DPP+shfl reduction) (r11 best) ----------------
__device__ __forceinline__ void attn2_batch(const uint32* u, const float* d,
                                            float2 rv, float2 av, float base,
                                            float& s, float& a0, float& a1){
  float x00 = bflo(u[0]), x01 = bfhi(u[0]);
  float x10 = bflo(u[1]), x11 = bfhi(u[1]);
  float x20 = bflo(u[2]), x21 = bfhi(u[2]);
  float x30 = bflo(u[3]), x31 = bfhi(u[3]);
  float p0 = fmaf(av.x, fabsf(x00 + rv.x), av.y * fabsf(x01 + rv.y));
  float p1 = fmaf(av.x, fabsf(x10 + rv.x), av.y * fabsf(x11 + rv.y));
  float p2 = fmaf(av.x, fabsf(x20 + rv.x), av.y * fabsf(x21 + rv.y));
  float p3 = fmaf(av.x, fabsf(x30 + rv.x), av.y * fabsf(x31 + rv.y));
  p0 = red64(p0); p1 = red64(p1); p2 = red64(p2); p3 = red64(p3);
  float ex0 = __expf(fmaf(0.4f, p0, fmaf(0.6f, d[0], base)));
  float ex1 = __expf(fmaf(0.4f, p1, fmaf(0.6f, d[1], base)));
  float ex2 = __expf(fmaf(0.4f, p2, fmaf(0.6f, d[2], base)));
  float ex3 = __expf(fmaf(0.4f, p3, fmaf(0.6f, d[3], base)));
  s += (ex0 + ex1) + (ex2 + ex3);
  float t0 = fmaf(ex0, x00, ex1 * x10); t0 = fmaf(ex2, x20, t0);
  float t1 = fmaf(ex0, x01, ex1 * x11); t1 = fmaf(ex2, x21, t1);
  a0 = fmaf(ex3, x30, a0 + t0);
  a1 = fmaf(ex3, x31, a1 + t1);
}

// ---------------- layer-2 GATv2 + fused output GEMM, 16 waves/block wave-per-node (r11 best) ----------------
__global__ __launch_bounds__(1024) void k_attn2(const unsigned short* __restrict__ xl,
                                                const float* __restrict__ xr,
                                                const float* __restrict__ dl, const float* __restrict__ dr,
                                                const float* __restrict__ att, const float* __restrict__ bias,
                                                const float* __restrict__ outW, const float* __restrict__ outb,
                                                const int* __restrict__ gmax,
                                                const int* __restrict__ off, const int* __restrict__ csr,
                                                float* __restrict__ out){
  __shared__ float Wsh[1280];
  int tid = threadIdx.x;
  for (int i = tid; i < 1280; i += 1024) Wsh[i] = outW[i];
  __syncthreads();
  int lane = tid & 63;
  int n = blockIdx.x * 16 + (tid >> 6);
  float2 rv = *(const float2*)(xr + (size_t)n * 128 + lane * 2);
  float2 av = *(const float2*)(att + lane * 2);
  float V = red64(fmaf(fabsf(av.x), fabsf(rv.x), fabsf(av.y) * fabsf(rv.y)));
  float Mg = (float)(gmax[0] - (1 << 30)) * (1.0f / 256.0f);
  float base = fmaf(0.6f, dr[n], -Mg - 0.4f * V);
  int beg = off[n], end = off[n + 1];
  int cnt = end - beg;
  int nfull = cnt >> 2;
  float s = 0.f;
  float a0 = 0.f, a1 = 0.f;
  uint32 uA[4], uB[4];
  float dA[4], dB[4];
  int j = beg;
  if (nfull > 0){
    int s0 = csr[j], s1 = csr[j+1], s2 = csr[j+2], s3 = csr[j+3];
    uA[0] = *(const uint32*)(xl + (size_t)s0 * 128 + lane * 2);
    uA[1] = *(const uint32*)(xl + (size_t)s1 * 128 + lane * 2);
    uA[2] = *(const uint32*)(xl + (size_t)s2 * 128 + lane * 2);
    uA[3] = *(const uint32*)(xl + (size_t)s3 * 128 + lane * 2);
    dA[0] = dl[s0]; dA[1] = dl[s1]; dA[2] = dl[s2]; dA[3] = dl[s3];
  }
  for (int b = 0; b < nfull; b++){
    int jn = j + 4;
    if (b + 1 < nfull){
      int s0 = csr[jn], s1 = csr[jn+1], s2 = csr[jn+2], s3 = csr[jn+3];
      uB[0] = *(const uint32*)(xl + (size_t)s0 * 128 + lane * 2);
      uB[1] = *(const uint32*)(xl + (size_t)s1 * 128 + lane * 2);
      uB[2] = *(const uint32*)(xl + (size_t)s2 * 128 + lane * 2);
      uB[3] = *(const uint32*)(xl + (size_t)s3 * 128 + lane * 2);
      dB[0] = dl[s0]; dB[1] = dl[s1]; dB[2] = dl[s2]; dB[3] = dl[s3];
    }
    attn2_batch(uA, dA, rv, av, base, s, a0, a1);
    j = jn;
    #pragma unroll
    for (int i = 0; i < 4; i++){ uA[i] = uB[i]; dA[i] = dB[i]; }
  }
  for (; j < end; j++){
    int sn = csr[j];
    float dls = dl[sn];
    uint32 u = *(const uint32*)(xl + (size_t)sn * 128 + lane * 2);
    float x0 = bflo(u), x1 = bfhi(u);
    float p = red64(fmaf(av.x, fabsf(x0 + rv.x), av.y * fabsf(x1 + rv.y)));
    float ex = __expf(fmaf(0.4f, p, fmaf(0.6f, dls, base)));
    s += ex;
    a0 = fmaf(ex, x0, a0);
    a1 = fmaf(ex, x1, a1);
  }
  float inv = 1.f / (s + 1e-16f);
  int c = lane * 2;
  float x2_0 = fmaf(a0, inv, bias[c]);
  float x2_1 = fmaf(a1, inv, bias[c + 1]);
  #pragma unroll
  for (int o = 0; o < 10; o++){
    float p = fmaf(x2_0, Wsh[c * 10 + o], x2_1 * Wsh[(c + 1) * 10 + o]);
    p = red64(p);
    if (lane == 0) out[(size_t)n * 10 + o] = p + outb[o];
  }
}

extern "C" void kernel_launch(void* const* d_in, const int* in_sizes, int n_in,
                              void* d_out, int out_size, void* d_ws, size_t ws_size,
                              hipStream_t stream){
  const float* xp    = (const float*)d_in[0];
  const int*   ei    = (const int*)  d_in[1];
  const float* emb   = (const float*)d_in[2];
  const float* projW = (const float*)d_in[3];
  const float* projb = (const float*)d_in[4];
  const float* W1l   = (const float*)d_in[5];
  const float* W1r   = (const float*)d_in[6];
  const float* att1  = (const float*)d_in[7];
  const float* b1    = (const float*)d_in[8];
  const float* W2l   = (const float*)d_in[9];
  const float* W2r   = (const float*)d_in[10];
  const float* att2  = (const float*)d_in[11];
  const float* b2    = (const float*)d_in[12];
  const float* outW  = (const float*)d_in[13];
  const float* outb  = (const float*)d_in[14];
  float* out = (float*)d_out;

  int E = in_sizes[1] / 2;
  const int* esrc = ei;
  const int* edst = ei + E;

  char* w = (char*)d_ws;
  int* gmaxi = (int*)w; w += 32;            // [0..3] layer1 heads, [4] layer2
  int* deg  = (int*)w; w += (size_t)NNODES * 4;
  int* off  = (int*)w; w += (size_t)(NNODES + 4) * 4;
  int* cur  = (int*)w; w += (size_t)NNODES * 4;
  int* csr  = (int*)w; w += (size_t)(NNODES + E) * 4;
  unsigned short* Xb   = (unsigned short*)w; w += (size_t)NNODES * 128 * 2;
  unsigned short* Wt1l = (unsigned short*)w; w += (size_t)512 * 128 * 2;
  unsigned short* Wt1r = (unsigned short*)w; w += (size_t)512 * 128 * 2;
  unsigned short* Wt2l = (unsigned short*)w; w += (size_t)128 * 512 * 2;
  unsigned short* Wt2r = (unsigned short*)w; w += (size_t)128 * 512 * 2;
  unsigned short* Wtp  = (unsigned short*)w; w += (size_t)128 * 192 * 2;
  unsigned short* xl1b = (unsigned short*)w; w += (size_t)NNODES * 512 * 2;
  unsigned short* xr1b = (unsigned short*)w; w += (size_t)NNODES * 512 * 2;
  unsigned short* X1b  = (unsigned short*)w; w += (size_t)NNODES * 512 * 2;
  unsigned short* xl2b = (unsigned short*)w; w += (size_t)NNODES * 128 * 2;
  float* xr2 = (float*)w; w += (size_t)NNODES * 128 * 4;
  float* dl1 = (float*)w; w += (size_t)NNODES * 4 * 4;
  float* dr1 = (float*)w; w += (size_t)NNODES * 4 * 4;
  float* dl2 = (float*)w; w += (size_t)NNODES * 4;
  float* dr2 = (float*)w; w += (size_t)NNODES * 4;

  hipMemsetAsync(gmaxi, 0, 32 + (size_t)NNODES * 4, stream);  // covers gmaxi + deg
  int cvt_total = E + 286720;
  k_cvt_count<<<(cvt_total + 255) / 256, 256, 0, stream>>>(
      edst, E, deg, W1l, W1r, W2l, W2r, projW, Wt1l, Wt1r, Wt2l, Wt2r, Wtp);
  k_scan<<<1, 256, 0, stream>>>(deg, off, cur);
  k_fill<<<(NNODES + E + 255) / 256, 256, 0, stream>>>(esrc, edst, E, cur, csr);

  k_proj_mfma<<<dim3((NNODES + 63) / 64), 256, 0, stream>>>(xp, emb, Wtp, projb, Xb);
  k_mfma<128, 512, 0, 4><<<dim3(4, (NNODES + 63) / 64, 2), 256, 0, stream>>>(
      Xb, Wt1l, Wt1r, xl1b, xr1b, att1, dl1, dr1, gmaxi);
  k_attn1<<<NNODES, 256, 0, stream>>>(xl1b, xr1b, dl1, dr1, att1, b1, gmaxi, off, csr, X1b);
  k_mfma<512, 128, 1, 1><<<dim3(1, (NNODES + 63) / 64, 2), 256, 0, stream>>>(
      X1b, Wt2l, Wt2r, xl2b, xr2, att2, dl2, dr2, gmaxi + 4);
  k_attn2<<<NNODES / 16, 1024, 0, stream>>>(xl2b, xr2, dl2, dr2, att2, b2, outW, outb, gmaxi + 4, off, csr, out);
}

// Round 16
// 285.502 us; speedup vs baseline: 1.0673x; 1.0045x over previous
//
#include <hip/hip_runtime.h>
#include <math.h>

#define NNODES 20000
#define XP_COLS 65

typedef unsigned int uint32;
typedef __attribute__((ext_vector_type(8))) short short8;
typedef __attribute__((ext_vector_type(4))) float float4v;

__device__ __forceinline__ float bflo(uint32 u){ return __uint_as_float(u << 16); }
__device__ __forceinline__ float bfhi(uint32 u){ return __uint_as_float(u & 0xffff0000u); }
__device__ __forceinline__ unsigned short f2bf(float f){
  uint32 u = __float_as_uint(f);
  uint32 r = (u + 0x7fffu + ((u >> 16) & 1u)) >> 16;
  return (unsigned short)r;
}
__device__ __forceinline__ void unpack8(uint4 u, float* x){
  x[0]=bflo(u.x); x[1]=bfhi(u.x); x[2]=bflo(u.y); x[3]=bfhi(u.y);
  x[4]=bflo(u.z); x[5]=bfhi(u.z); x[6]=bflo(u.w); x[7]=bfhi(u.w);
}
// sum across each 16-lane row via DPP row_ror (VALU-only, no LDS pipe)
__device__ __forceinline__ float rowsum16(float x){
  x += __int_as_float(__builtin_amdgcn_update_dpp(0, __float_as_int(x), 0x121, 0xf, 0xf, true));
  x += __int_as_float(__builtin_amdgcn_update_dpp(0, __float_as_int(x), 0x122, 0xf, 0xf, true));
  x += __int_as_float(__builtin_amdgcn_update_dpp(0, __float_as_int(x), 0x124, 0xf, 0xf, true));
  x += __int_as_float(__builtin_amdgcn_update_dpp(0, __float_as_int(x), 0x128, 0xf, 0xf, true));
  return x;
}
__device__ __forceinline__ float red64(float p){
  p = rowsum16(p);
  p += __shfl_xor(p, 16);
  p += __shfl_xor(p, 32);
  return p;
}

// ---------------- fused: edge-degree count + LDS-tiled weight transpose/cast ----------------
// blocks [0, CB): edge-degree atomics. blocks [CB, CB+280): one 32x32 transpose tile each.
__global__ __launch_bounds__(256) void k_cvt_count(const int* __restrict__ dst, int E, int CB,
                            int* __restrict__ deg,
                            const float* __restrict__ W1l, const float* __restrict__ W1r,
                            const float* __restrict__ W2l, const float* __restrict__ W2r,
                            const float* __restrict__ projW,
                            unsigned short* __restrict__ T1l, unsigned short* __restrict__ T1r,
                            unsigned short* __restrict__ T2l, unsigned short* __restrict__ T2r,
                            unsigned short* __restrict__ Tp){
  __shared__ float tile[32][33];
  int bid = blockIdx.x;
  if (bid < CB){
    int e = bid * 256 + threadIdx.x;
    if (e < E) atomicAdd(&deg[dst[e]], 1);
    return;
  }
  int t = bid - CB;
  const float* S; unsigned short* D;
  int SK, SN, kt, nt;
  if (t < 64){        S = W1l; D = T1l; SK = 128; SN = 512; int q = t;        kt = q & 3;  nt = q >> 2; }
  else if (t < 128){  S = W1r; D = T1r; SK = 128; SN = 512; int q = t - 64;   kt = q & 3;  nt = q >> 2; }
  else if (t < 192){  S = W2l; D = T2l; SK = 512; SN = 128; int q = t - 128;  kt = q & 15; nt = q >> 4; }
  else if (t < 256){  S = W2r; D = T2r; SK = 512; SN = 128; int q = t - 192;  kt = q & 15; nt = q >> 4; }
  else {              S = projW; D = Tp; SK = 192; SN = 128; int q = t - 256; kt = q % 6;  nt = q / 6; }
  int tid = threadIdx.x;
  int c = tid & 31, r0 = tid >> 5;           // 8 rows per pass
  #pragma unroll
  for (int i = 0; i < 4; i++){
    int r = r0 + i * 8;
    tile[r][c] = S[(size_t)(kt * 32 + r) * SN + nt * 32 + c];   // coalesced over n
  }
  __syncthreads();
  #pragma unroll
  for (int i = 0; i < 4; i++){
    int r = r0 + i * 8;                       // dest row within tile (n-dim)
    D[(size_t)(nt * 32 + r) * SK + kt * 32 + c] = f2bf(tile[c][r]);  // coalesced over k
  }
}

// chunked scan, int4-vectorized; deg[i]+1 accounts for self loop (deg pre-memset to 0)
__global__ __launch_bounds__(256) void k_scan(const int* __restrict__ deg,
                                              int* __restrict__ off,
                                              int* __restrict__ cursor){
  const int CH = 80;
  int tid = threadIdx.x;
  int lane = tid & 63, w = tid >> 6;
  int beg = tid * CH;
  bool act = beg < NNODES;
  int sum = 0;
  if (act){
    const int4* p = (const int4*)(deg + beg);
    #pragma unroll
    for (int i = 0; i < 20; i++){
      int4 v = p[i];
      sum += v.x + v.y + v.z + v.w + 4;
    }
  }
  int inc = sum;
  #pragma unroll
  for (int d = 1; d < 64; d <<= 1){
    int t = __shfl_up(inc, d, 64);
    if (lane >= d) inc += t;
  }
  __shared__ int wtot[4];
  if (lane == 63) wtot[w] = inc;
  __syncthreads();
  int wbase = 0;
  for (int i = 0; i < w; i++) wbase += wtot[i];
  int run = wbase + inc - sum;
  if (act){
    const int4* p = (const int4*)(deg + beg);
    int4* po = (int4*)(off + beg);
    int4* pc = (int4*)(cursor + beg);
    #pragma unroll
    for (int i = 0; i < 20; i++){
      int4 v = p[i];
      int4 o;
      o.x = run; run += v.x + 1;
      o.y = run; run += v.y + 1;
      o.z = run; run += v.z + 1;
      o.w = run; run += v.w + 1;
      po[i] = o; pc[i] = o;
    }
  }
  if (tid == 249) off[NNODES] = run;
}

__global__ void k_fill(const int* __restrict__ src, const int* __restrict__ dst, int E,
                       int* __restrict__ cursor, int* __restrict__ csr){
  int t = blockIdx.x * 256 + threadIdx.x;
  if (t < NNODES){
    int p = atomicAdd(&cursor[t], 1);
    csr[p] = t;
  } else if (t < NNODES + E){
    int e = t - NNODES;
    int p = atomicAdd(&cursor[dst[e]], 1);
    csr[p] = src[e];
  }
}

// ---------------- proj via MFMA with fused gather ----------------
__global__ __launch_bounds__(256) void k_proj_mfma(const float* __restrict__ xp,
                                                   const float* __restrict__ emb,
                                                   const unsigned short* __restrict__ Bt,
                                                   const float* __restrict__ bias,
                                                   unsigned short* __restrict__ Xb){
  __shared__ unsigned short As[64][40];
  __shared__ unsigned short Bs[128][40];
  __shared__ int ids[64];
  int tid = threadIdx.x;
  int bm = blockIdx.x * 64;
  int w = tid >> 6, lane = tid & 63;
  int wm = (w >> 1) * 32, wn = (w & 1) * 64;
  int quad = lane >> 4, l16 = lane & 15;
  if (tid < 64){
    int g = bm + tid;
    ids[tid] = (g < NNODES) ? (int)xp[(size_t)g * XP_COLS] : 0;
  }
  float4v acc[2][4];
  #pragma unroll
  for (int i = 0; i < 2; i++)
    #pragma unroll
    for (int j = 0; j < 4; j++) acc[i][j] = (float4v){0.f,0.f,0.f,0.f};
  int am = tid >> 2, ak = (tid & 3) * 8;
  int gm = bm + am;
  bool mv = gm < NNODES;
  int brow = tid >> 1, bk = (tid & 1) * 16;
  __syncthreads();

  for (int k0 = 0; k0 < 192; k0 += 32){
    float v[8];
    if (k0 < 128){
      const float* ep = emb + (size_t)ids[am] * 128 + k0 + ak;
      float4 e0 = *(const float4*)ep;
      float4 e1 = *(const float4*)(ep + 4);
      v[0]=e0.x; v[1]=e0.y; v[2]=e0.z; v[3]=e0.w;
      v[4]=e1.x; v[5]=e1.y; v[6]=e1.z; v[7]=e1.w;
    } else {
      const float* fp = xp + (size_t)gm * XP_COLS + 1 + (k0 - 128) + ak;
      #pragma unroll
      for (int i = 0; i < 8; i++) v[i] = mv ? fp[i] : 0.f;
    }
    ushort4 o0, o1;
    o0.x=f2bf(v[0]); o0.y=f2bf(v[1]); o0.z=f2bf(v[2]); o0.w=f2bf(v[3]);
    o1.x=f2bf(v[4]); o1.y=f2bf(v[5]); o1.z=f2bf(v[6]); o1.w=f2bf(v[7]);
    *(ushort4*)&As[am][ak]     = o0;
    *(ushort4*)&As[am][ak + 4] = o1;
    const unsigned short* bp = Bt + (size_t)brow * 192 + k0 + bk;
    *(uint4*)&Bs[brow][bk]     = *(const uint4*)bp;
    *(uint4*)&Bs[brow][bk + 8] = *(const uint4*)(bp + 8);
    __syncthreads();
    short8 af[2], bf[4];
    #pragma unroll
    for (int t = 0; t < 2; t++) af[t] = *(const short8*)&As[wm + t * 16 + l16][quad * 8];
    #pragma unroll
    for (int t = 0; t < 4; t++) bf[t] = *(const short8*)&Bs[wn + t * 16 + l16][quad * 8];
    #pragma unroll
    for (int tm = 0; tm < 2; tm++)
      #pragma unroll
      for (int tn = 0; tn < 4; tn++)
        acc[tm][tn] = __builtin_amdgcn_mfma_f32_16x16x32_bf16(af[tm], bf[tn], acc[tm][tn], 0, 0, 0);
    __syncthreads();
  }
  #pragma unroll
  for (int tm = 0; tm < 2; tm++){
    #pragma unroll
    for (int r = 0; r < 4; r++){
      int row = bm + wm + tm * 16 + quad * 4 + r;
      if (row >= NNODES) continue;
      #pragma unroll
      for (int tn = 0; tn < 4; tn++){
        int col = wn + tn * 16 + l16;
        float val = fmaxf(acc[tm][tn][r] + bias[col], 0.f);
        Xb[(size_t)row * 128 + col] = f2bf(val);
      }
    }
  }
}

// ---------------- MFMA GEMM with fused per-row attention dot + abs-dot bound ----------------
template<int K, int N, int MODE, int NH>
__global__ __launch_bounds__(256) void k_mfma(const unsigned short* __restrict__ A,
                                              const unsigned short* __restrict__ B0t,
                                              const unsigned short* __restrict__ B1t,
                                              void* __restrict__ C0, void* __restrict__ C1,
                                              const float* __restrict__ att,
                                              float* __restrict__ dl, float* __restrict__ dr,
                                              int* __restrict__ gmax){
  const unsigned short* Bt = blockIdx.z ? B1t : B0t;
  __shared__ unsigned short As[64][40];
  __shared__ unsigned short Bs[128][40];
  __shared__ float red[4][32];
  __shared__ float redu[4][32];
  int tid = threadIdx.x;
  int bm = blockIdx.y * 64;
  int bn = blockIdx.x * 128;
  int head = (NH == 1) ? 0 : blockIdx.x;
  int w = tid >> 6, lane = tid & 63;
  int wm = (w >> 1) * 32, wn = (w & 1) * 64;
  int quad = lane >> 4, l16 = lane & 15;
  float av[4], aav[4];
  #pragma unroll
  for (int tn = 0; tn < 4; tn++){
    av[tn] = att[head * 128 + wn + tn * 16 + l16];
    aav[tn] = fabsf(av[tn]);
  }
  float4v acc[2][4];
  #pragma unroll
  for (int i = 0; i < 2; i++)
    #pragma unroll
    for (int j = 0; j < 4; j++) acc[i][j] = (float4v){0.f,0.f,0.f,0.f};
  int am = tid >> 2, ak = (tid & 3) * 8;
  int gm = bm + am;
  bool mv = gm < NNODES;
  int brow = tid >> 1, bk = (tid & 1) * 16;

  for (int k0 = 0; k0 < K; k0 += 32){
    uint4 va = {0u,0u,0u,0u};
    if (mv) va = *(const uint4*)(A + (size_t)gm * K + k0 + ak);
    *(uint4*)&As[am][ak] = va;
    const unsigned short* bp = Bt + (size_t)(bn + brow) * K + k0 + bk;
    *(uint4*)&Bs[brow][bk]     = *(const uint4*)bp;
    *(uint4*)&Bs[brow][bk + 8] = *(const uint4*)(bp + 8);
    __syncthreads();
    short8 af[2], bf[4];
    #pragma unroll
    for (int t = 0; t < 2; t++) af[t] = *(const short8*)&As[wm + t * 16 + l16][quad * 8];
    #pragma unroll
    for (int t = 0; t < 4; t++) bf[t] = *(const short8*)&Bs[wn + t * 16 + l16][quad * 8];
    #pragma unroll
    for (int tm = 0; tm < 2; tm++)
      #pragma unroll
      for (int tn = 0; tn < 4; tn++)
        acc[tm][tn] = __builtin_amdgcn_mfma_f32_16x16x32_bf16(af[tm], bf[tn], acc[tm][tn], 0, 0, 0);
    __syncthreads();
  }
  #pragma unroll
  for (int tm = 0; tm < 2; tm++){
    #pragma unroll
    for (int r = 0; r < 4; r++){
      int row = bm + wm + tm * 16 + quad * 4 + r;
      if (row < NNODES){
        #pragma unroll
        for (int tn = 0; tn < 4; tn++){
          int col = bn + wn + tn * 16 + l16;
          float val = acc[tm][tn][r];
          if (MODE == 0 || blockIdx.z == 0){
            unsigned short* C = (unsigned short*)(blockIdx.z ? C1 : C0);
            C[(size_t)row * N + col] = f2bf(val);
          } else {
            ((float*)C1)[(size_t)row * N + col] = val;
          }
        }
      }
      float pd = acc[tm][0][r] * av[0];
      pd = fmaf(acc[tm][1][r], av[1], pd);
      pd = fmaf(acc[tm][2][r], av[2], pd);
      pd = fmaf(acc[tm][3][r], av[3], pd);
      float pu = fabsf(acc[tm][0][r]) * aav[0];
      pu = fmaf(fabsf(acc[tm][1][r]), aav[1], pu);
      pu = fmaf(fabsf(acc[tm][2][r]), aav[2], pu);
      pu = fmaf(fabsf(acc[tm][3][r]), aav[3], pu);
      pd = rowsum16(pd);
      pu = rowsum16(pu);
      if (l16 == 0){
        red[w][tm * 16 + quad * 4 + r]  = pd;
        redu[w][tm * 16 + quad * 4 + r] = pu;
      }
    }
  }
  __syncthreads();
  if (tid < 64){
    float vd, vu;
    if (tid < 32){ vd = red[0][tid] + red[1][tid];   vu = redu[0][tid] + redu[1][tid]; }
    else { vd = red[2][tid & 31] + red[3][tid & 31]; vu = redu[2][tid & 31] + redu[3][tid & 31]; }
    int row = bm + tid;
    bool ok = row < NNODES;
    if (ok){
      float* D = blockIdx.z ? dr : dl;
      D[row * NH + head] = vd;
    }
    if (blockIdx.z == 0){
      float v = ok ? fmaf(0.4f, vu, 0.6f * vd) : -4.0e6f;
      #pragma unroll
      for (int dd = 1; dd < 64; dd <<= 1) v = fmaxf(v, __shfl_xor(v, dd));
      if (tid == 0) atomicMax(&gmax[head], (int)ceilf(v * 256.0f) + (1 << 30));
    }
  }
}

// ---------------- layer-1 GATv2: block per node, round-robin 4-edge batches per wave (r13 best) ----------------
__global__ __launch_bounds__(256) void k_attn1(const unsigned short* __restrict__ xl,
                                               const unsigned short* __restrict__ xr,
                                               const float* __restrict__ dl, const float* __restrict__ dr,
                                               const float* __restrict__ att, const float* __restrict__ bias,
                                               const int* __restrict__ gmax,
                                               const int* __restrict__ off, const int* __restrict__ csr,
                                               unsigned short* __restrict__ out){
  int tid = threadIdx.x;
  int w = tid >> 6, lane = tid & 63;
  int n = blockIdx.x;
  int h = lane >> 4;
  uint4 ur = *(const uint4*)(xr + (size_t)n * 512 + lane * 8);
  float r[8]; unpack8(ur, r);
  const float* ap = att + lane * 8;
  float4 A0 = *(const float4*)ap, A1 = *(const float4*)(ap + 4);
  float a[8] = {A0.x,A0.y,A0.z,A0.w,A1.x,A1.y,A1.z,A1.w};
  float V = 0.f;
  #pragma unroll
  for (int i = 0; i < 8; i++) V = fmaf(fabsf(a[i]), fabsf(r[i]), V);
  V = rowsum16(V);
  float Mg = (float)(gmax[h] - (1 << 30)) * (1.0f / 256.0f);
  float base = fmaf(0.6f, dr[n * 4 + h], -Mg - 0.4f * V);
  int beg = off[n], end = off[n + 1];
  int cnt = end - beg;
  int B = (cnt + 3) >> 2;                 // 4-edge batches over whole list

  float s = 0.f;
  float acc[8] = {0,0,0,0,0,0,0,0};
  for (int b = w; b < B; b += 4){
    int j0 = beg + b * 4;
    int i1 = j0 + 1, i2 = j0 + 2, i3 = j0 + 3;
    float m1 = 1.f, m2 = 1.f, m3 = 1.f;
    if (i1 >= end){ i1 = j0; m1 = 0.f; }
    if (i2 >= end){ i2 = j0; m2 = 0.f; }
    if (i3 >= end){ i3 = j0; m3 = 0.f; }
    int s0 = csr[j0], s1 = csr[i1], s2 = csr[i2], s3 = csr[i3];
    uint4 u0 = *(const uint4*)(xl + (size_t)s0 * 512 + lane * 8);
    uint4 u1 = *(const uint4*)(xl + (size_t)s1 * 512 + lane * 8);
    uint4 u2 = *(const uint4*)(xl + (size_t)s2 * 512 + lane * 8);
    uint4 u3 = *(const uint4*)(xl + (size_t)s3 * 512 + lane * 8);
    float d0 = dl[s0 * 4 + h], d1 = dl[s1 * 4 + h];
    float d2 = dl[s2 * 4 + h], d3 = dl[s3 * 4 + h];
    float x0[8], x1[8], x2[8], x3[8];
    unpack8(u0, x0); unpack8(u1, x1); unpack8(u2, x2); unpack8(u3, x3);
    float p0 = 0.f, p1 = 0.f, p2 = 0.f, p3 = 0.f;
    #pragma unroll
    for (int i = 0; i < 8; i++){
      p0 = fmaf(a[i], fabsf(x0[i] + r[i]), p0);
      p1 = fmaf(a[i], fabsf(x1[i] + r[i]), p1);
      p2 = fmaf(a[i], fabsf(x2[i] + r[i]), p2);
      p3 = fmaf(a[i], fabsf(x3[i] + r[i]), p3);
    }
    p0 = rowsum16(p0); p1 = rowsum16(p1); p2 = rowsum16(p2); p3 = rowsum16(p3);
    float ex0 = __expf(fmaf(0.4f, p0, fmaf(0.6f, d0, base)));
    float ex1 = __expf(fmaf(0.4f, p1, fmaf(0.6f, d1, base))) * m1;
    float ex2 = __expf(fmaf(0.4f, p2, fmaf(0.6f, d2, base))) * m2;
    float ex3 = __expf(fmaf(0.4f, p3, fmaf(0.6f, d3, base))) * m3;
    s += (ex0 + ex1) + (ex2 + ex3);
    #pragma unroll
    for (int i = 0; i < 8; i++){
      float t = fmaf(ex0, x0[i], ex1 * x1[i]);
      t = fmaf(ex2, x2[i], t);
      acc[i] = fmaf(ex3, x3[i], acc[i] + t);
    }
  }
  __shared__ float accsh[4][512];
  __shared__ float ssh[4][4];
  *(float4*)&accsh[w][lane * 8]     = make_float4(acc[0], acc[1], acc[2], acc[3]);
  *(float4*)&accsh[w][lane * 8 + 4] = make_float4(acc[4], acc[5], acc[6], acc[7]);
  if ((lane & 15) == 0) ssh[w][h] = s;
  __syncthreads();
  for (int c = tid; c < 512; c += 256){
    float v = (accsh[0][c] + accsh[1][c]) + (accsh[2][c] + accsh[3][c]);
    int hh = c >> 7;
    float sv = (ssh[0][hh] + ssh[1][hh]) + (ssh[2][hh] + ssh[3][hh]);
    float o = v / (sv + 1e-16f) + bias[c];
    out[(size_t)n * 512 + c] = f2bf(fmaxf(o, 0.f));
  }
}

// ---------------- attn2 batch compute (4 edges, branch-free, DPP+shfl reduction) (r11 best) ----------------
__device__ __forceinline__ void attn2_batch(const uint32* u, const float* d,
                                            float2 rv, float2 av, float base,
                                            float& s, float& a0, float& a1){
  float x00 = bflo(u[0]), x01 = bfhi(u[0]);
  float x10 = bflo(u[1]), x11 = bfhi(u[1]);
  float x20 = bflo(u[2]), x21 = bfhi(u[2]);
  float x30 = bflo(u[3]), x31 = bfhi(u[3]);
  float p0 = fmaf(av.x, fabsf(x00 + rv.x), av.y * fabsf(x01 + rv.y));
  float p1 = fmaf(av.x, fabsf(x10 + rv.x), av.y * fabsf(x11 + rv.y));
  float p2 = fmaf(av.x, fabsf(x20 + rv.x), av.y * fabsf(x21 + rv.y));
  float p3 = fmaf(av.x, fabsf(x30 + rv.x), av.y * fabsf(x31 + rv.y));
  p0 = red64(p0); p1 = red64(p1); p2 = red64(p2); p3 = red64(p3);
  float ex0 = __expf(fmaf(0.4f, p0, fmaf(0.6f, d[0], base)));
  float ex1 = __expf(fmaf(0.4f, p1, fmaf(0.6f, d[1], base)));
  float ex2 = __expf(fmaf(0.4f, p2, fmaf(0.6f, d[2], base)));
  float ex3 = __expf(fmaf(0.4f, p3, fmaf(0.6f, d[3], base)));
  s += (ex0 + ex1) + (ex2 + ex3);
  float t0 = fmaf(ex0, x00, ex1 * x10); t0 = fmaf(ex2, x20, t0);
  float t1 = fmaf(ex0, x01, ex1 * x11); t1 = fmaf(ex2, x21, t1);
  a0 = fmaf(ex3, x30, a0 + t0);
  a1 = fmaf(ex3, x31, a1 + t1);
}

// ---------------- layer-2 GATv2 + fused output GEMM, 16 waves/block wave-per-node (r11 best) ----------------
__global__ __launch_bounds__(1024) void k_attn2(const unsigned short* __restrict__ xl,
                                                const float* __restrict__ xr,
                                                const float* __restrict__ dl, const float* __restrict__ dr,
                                                const float* __restrict__ att, const float* __restrict__ bias,
                                                const float* __restrict__ outW, const float* __restrict__ outb,
                                                const int* __restrict__ gmax,
                                                const int* __restrict__ off, const int* __restrict__ csr,
                                                float* __restrict__ out){
  __shared__ float Wsh[1280];
  int tid = threadIdx.x;
  for (int i = tid; i < 1280; i += 1024) Wsh[i] = outW[i];
  __syncthreads();
  int lane = tid & 63;
  int n = blockIdx.x * 16 + (tid >> 6);
  float2 rv = *(const float2*)(xr + (size_t)n * 128 + lane * 2);
  float2 av = *(const float2*)(att + lane * 2);
  float V = red64(fmaf(fabsf(av.x), fabsf(rv.x), fabsf(av.y) * fabsf(rv.y)));
  float Mg = (float)(gmax[0] - (1 << 30)) * (1.0f / 256.0f);
  float base = fmaf(0.6f, dr[n], -Mg - 0.4f * V);
  int beg = off[n], end = off[n + 1];
  int cnt = end - beg;
  int nfull = cnt >> 2;
  float s = 0.f;
  float a0 = 0.f, a1 = 0.f;
  uint32 uA[4], uB[4];
  float dA[4], dB[4];
  int j = beg;
  if (nfull > 0){
    int s0 = csr[j], s1 = csr[j+1], s2 = csr[j+2], s3 = csr[j+3];
    uA[0] = *(const uint32*)(xl + (size_t)s0 * 128 + lane * 2);
    uA[1] = *(const uint32*)(xl + (size_t)s1 * 128 + lane * 2);
    uA[2] = *(const uint32*)(xl + (size_t)s2 * 128 + lane * 2);
    uA[3] = *(const uint32*)(xl + (size_t)s3 * 128 + lane * 2);
    dA[0] = dl[s0]; dA[1] = dl[s1]; dA[2] = dl[s2]; dA[3] = dl[s3];
  }
  for (int b = 0; b < nfull; b++){
    int jn = j + 4;
    if (b + 1 < nfull){
      int s0 = csr[jn], s1 = csr[jn+1], s2 = csr[jn+2], s3 = csr[jn+3];
      uB[0] = *(const uint32*)(xl + (size_t)s0 * 128 + lane * 2);
      uB[1] = *(const uint32*)(xl + (size_t)s1 * 128 + lane * 2);
      uB[2] = *(const uint32*)(xl + (size_t)s2 * 128 + lane * 2);
      uB[3] = *(const uint32*)(xl + (size_t)s3 * 128 + lane * 2);
      dB[0] = dl[s0]; dB[1] = dl[s1]; dB[2] = dl[s2]; dB[3] = dl[s3];
    }
    attn2_batch(uA, dA, rv, av, base, s, a0, a1);
    j = jn;
    #pragma unroll
    for (int i = 0; i < 4; i++){ uA[i] = uB[i]; dA[i] = dB[i]; }
  }
  for (; j < end; j++){
    int sn = csr[j];
    float dls = dl[sn];
    uint32 u = *(const uint32*)(xl + (size_t)sn * 128 + lane * 2);
    float x0 = bflo(u), x1 = bfhi(u);
    float p = red64(fmaf(av.x, fabsf(x0 + rv.x), av.y * fabsf(x1 + rv.y)));
    float ex = __expf(fmaf(0.4f, p, fmaf(0.6f, dls, base)));
    s += ex;
    a0 = fmaf(ex, x0, a0);
    a1 = fmaf(ex, x1, a1);
  }
  float inv = 1.f / (s + 1e-16f);
  int c = lane * 2;
  float x2_0 = fmaf(a0, inv, bias[c]);
  float x2_1 = fmaf(a1, inv, bias[c + 1]);
  #pragma unroll
  for (int o = 0; o < 10; o++){
    float p = fmaf(x2_0, Wsh[c * 10 + o], x2_1 * Wsh[(c + 1) * 10 + o]);
    p = red64(p);
    if (lane == 0) out[(size_t)n * 10 + o] = p + outb[o];
  }
}

extern "C" void kernel_launch(void* const* d_in, const int* in_sizes, int n_in,
                              void* d_out, int out_size, void* d_ws, size_t ws_size,
                              hipStream_t stream){
  const float* xp    = (const float*)d_in[0];
  const int*   ei    = (const int*)  d_in[1];
  const float* emb   = (const float*)d_in[2];
  const float* projW = (const float*)d_in[3];
  const float* projb = (const float*)d_in[4];
  const float* W1l   = (const float*)d_in[5];
  const float* W1r   = (const float*)d_in[6];
  const float* att1  = (const float*)d_in[7];
  const float* b1    = (const float*)d_in[8];
  const float* W2l   = (const float*)d_in[9];
  const float* W2r   = (const float*)d_in[10];
  const float* att2  = (const float*)d_in[11];
  const float* b2    = (const float*)d_in[12];
  const float* outW  = (const float*)d_in[13];
  const float* outb  = (const float*)d_in[14];
  float* out = (float*)d_out;

  int E = in_sizes[1] / 2;
  const int* esrc = ei;
  const int* edst = ei + E;

  char* w = (char*)d_ws;
  int* gmaxi = (int*)w; w += 32;            // [0..3] layer1 heads, [4] layer2
  int* deg  = (int*)w; w += (size_t)NNODES * 4;
  int* off  = (int*)w; w += (size_t)(NNODES + 4) * 4;
  int* cur  = (int*)w; w += (size_t)NNODES * 4;
  int* csr  = (int*)w; w += (size_t)(NNODES + E) * 4;
  unsigned short* Xb   = (unsigned short*)w; w += (size_t)NNODES * 128 * 2;
  unsigned short* Wt1l = (unsigned short*)w; w += (size_t)512 * 128 * 2;
  unsigned short* Wt1r = (unsigned short*)w; w += (size_t)512 * 128 * 2;
  unsigned short* Wt2l = (unsigned short*)w; w += (size_t)128 * 512 * 2;
  unsigned short* Wt2r = (unsigned short*)w; w += (size_t)128 * 512 * 2;
  unsigned short* Wtp  = (unsigned short*)w; w += (size_t)128 * 192 * 2;
  unsigned short* xl1b = (unsigned short*)w; w += (size_t)NNODES * 512 * 2;
  unsigned short* xr1b = (unsigned short*)w; w += (size_t)NNODES * 512 * 2;
  unsigned short* X1b  = (unsigned short*)w; w += (size_t)NNODES * 512 * 2;
  unsigned short* xl2b = (unsigned short*)w; w += (size_t)NNODES * 128 * 2;
  float* xr2 = (float*)w; w += (size_t)NNODES * 128 * 4;
  float* dl1 = (float*)w; w += (size_t)NNODES * 4 * 4;
  float* dr1 = (float*)w; w += (size_t)NNODES * 4 * 4;
  float* dl2 = (float*)w; w += (size_t)NNODES * 4;
  float* dr2 = (float*)w; w += (size_t)NNODES * 4;

  hipMemsetAsync(gmaxi, 0, 32 + (size_t)NNODES * 4, stream);  // covers gmaxi + deg
  int CB = (E + 255) / 256;                  // count blocks
  k_cvt_count<<<CB + 280, 256, 0, stream>>>(
      edst, E, CB, deg, W1l, W1r, W2l, W2r, projW, Wt1l, Wt1r, Wt2l, Wt2r, Wtp);
  k_scan<<<1, 256, 0, stream>>>(deg, off, cur);
  k_fill<<<(NNODES + E + 255) / 256, 256, 0, stream>>>(esrc, edst, E, cur, csr);

  k_proj_mfma<<<dim3((NNODES + 63) / 64), 256, 0, stream>>>(xp, emb, Wtp, projb, Xb);
  k_mfma<128, 512, 0, 4><<<dim3(4, (NNODES + 63) / 64, 2), 256, 0, stream>>>(
      Xb, Wt1l, Wt1r, xl1b, xr1b, att1, dl1, dr1, gmaxi);
  k_attn1<<<NNODES, 256, 0, stream>>>(xl1b, xr1b, dl1, dr1, att1, b1, gmaxi, off, csr, X1b);
  k_mfma<512, 128, 1, 1><<<dim3(1, (NNODES + 63) / 64, 2), 256, 0, stream>>>(
      X1b, Wt2l, Wt2r, xl2b, xr2, att2, dl2, dr2, gmaxi + 4);
  k_attn2<<<NNODES / 16, 1024, 0, stream>>>(xl2b, xr2, dl2, dr2, att2, b2, outW, outb, gmaxi + 4, off, csr, out);
}

// Round 17
// 268.269 us; speedup vs baseline: 1.1358x; 1.0642x over previous
//
#include <hip/hip_runtime.h>
#include <math.h>

#define NNODES 20000
#define XP_COLS 65

typedef unsigned int uint32;
typedef __attribute__((ext_vector_type(8))) short short8;
typedef __attribute__((ext_vector_type(4))) float float4v;

__device__ __forceinline__ float bflo(uint32 u){ return __uint_as_float(u << 16); }
__device__ __forceinline__ float bfhi(uint32 u){ return __uint_as_float(u & 0xffff0000u); }
__device__ __forceinline__ unsigned short f2bf(float f){
  uint32 u = __float_as_uint(f);
  uint32 r = (u + 0x7fffu + ((u >> 16) & 1u)) >> 16;
  return (unsigned short)r;
}
__device__ __forceinline__ void unpack8(uint4 u, float* x){
  x[0]=bflo(u.x); x[1]=bfhi(u.x); x[2]=bflo(u.y); x[3]=bfhi(u.y);
  x[4]=bflo(u.z); x[5]=bfhi(u.z); x[6]=bflo(u.w); x[7]=bfhi(u.w);
}
// sum across each 16-lane row via DPP row_ror (VALU-only, no LDS pipe)
__device__ __forceinline__ float rowsum16(float x){
  x += __int_as_float(__builtin_amdgcn_update_dpp(0, __float_as_int(x), 0x121, 0xf, 0xf, true));
  x += __int_as_float(__builtin_amdgcn_update_dpp(0, __float_as_int(x), 0x122, 0xf, 0xf, true));
  x += __int_as_float(__builtin_amdgcn_update_dpp(0, __float_as_int(x), 0x124, 0xf, 0xf, true));
  x += __int_as_float(__builtin_amdgcn_update_dpp(0, __float_as_int(x), 0x128, 0xf, 0xf, true));
  return x;
}
__device__ __forceinline__ float red64(float p){
  p = rowsum16(p);
  p += __shfl_xor(p, 16);
  p += __shfl_xor(p, 32);
  return p;
}

// ---------------- fused: edge-degree count (stores rank) + LDS-tiled weight transpose/cast ----------------
__global__ __launch_bounds__(256) void k_cvt_count(const int* __restrict__ dst, int E, int CB,
                            int* __restrict__ deg, int* __restrict__ rank,
                            const float* __restrict__ W1l, const float* __restrict__ W1r,
                            const float* __restrict__ W2l, const float* __restrict__ W2r,
                            const float* __restrict__ projW,
                            unsigned short* __restrict__ T1l, unsigned short* __restrict__ T1r,
                            unsigned short* __restrict__ T2l, unsigned short* __restrict__ T2r,
                            unsigned short* __restrict__ Tp){
  __shared__ float tile[32][33];
  int bid = blockIdx.x;
  if (bid < CB){
    int e = bid * 256 + threadIdx.x;
    if (e < E) rank[e] = atomicAdd(&deg[dst[e]], 1);
    return;
  }
  int t = bid - CB;
  const float* S; unsigned short* D;
  int SK, SN, kt, nt;
  if (t < 64){        S = W1l; D = T1l; SK = 128; SN = 512; int q = t;        kt = q & 3;  nt = q >> 2; }
  else if (t < 128){  S = W1r; D = T1r; SK = 128; SN = 512; int q = t - 64;   kt = q & 3;  nt = q >> 2; }
  else if (t < 192){  S = W2l; D = T2l; SK = 512; SN = 128; int q = t - 128;  kt = q & 15; nt = q >> 4; }
  else if (t < 256){  S = W2r; D = T2r; SK = 512; SN = 128; int q = t - 192;  kt = q & 15; nt = q >> 4; }
  else {              S = projW; D = Tp; SK = 192; SN = 128; int q = t - 256; kt = q % 6;  nt = q / 6; }
  int tid = threadIdx.x;
  int c = tid & 31, r0 = tid >> 5;
  #pragma unroll
  for (int i = 0; i < 4; i++){
    int r = r0 + i * 8;
    tile[r][c] = S[(size_t)(kt * 32 + r) * SN + nt * 32 + c];
  }
  __syncthreads();
  #pragma unroll
  for (int i = 0; i < 4; i++){
    int r = r0 + i * 8;
    D[(size_t)(nt * 32 + r) * SK + kt * 32 + c] = f2bf(tile[c][r]);
  }
}

// chunked scan, int4-vectorized; deg[i]+1 accounts for self loop (deg pre-memset to 0)
__global__ __launch_bounds__(256) void k_scan(const int* __restrict__ deg,
                                              int* __restrict__ off){
  const int CH = 80;
  int tid = threadIdx.x;
  int lane = tid & 63, w = tid >> 6;
  int beg = tid * CH;
  bool act = beg < NNODES;
  int sum = 0;
  if (act){
    const int4* p = (const int4*)(deg + beg);
    #pragma unroll
    for (int i = 0; i < 20; i++){
      int4 v = p[i];
      sum += v.x + v.y + v.z + v.w + 4;
    }
  }
  int inc = sum;
  #pragma unroll
  for (int d = 1; d < 64; d <<= 1){
    int t = __shfl_up(inc, d, 64);
    if (lane >= d) inc += t;
  }
  __shared__ int wtot[4];
  if (lane == 63) wtot[w] = inc;
  __syncthreads();
  int wbase = 0;
  for (int i = 0; i < w; i++) wbase += wtot[i];
  int run = wbase + inc - sum;
  if (act){
    const int4* p = (const int4*)(deg + beg);
    int4* po = (int4*)(off + beg);
    #pragma unroll
    for (int i = 0; i < 20; i++){
      int4 v = p[i];
      int4 o;
      o.x = run; run += v.x + 1;
      o.y = run; run += v.y + 1;
      o.z = run; run += v.z + 1;
      o.w = run; run += v.w + 1;
      po[i] = o;
    }
  }
  if (tid == 249) off[NNODES] = run;
}

// atomic-free fill: edge e goes to slot off[dst]+rank[e]; self loop at off[n]+deg[n] (last)
__global__ void k_fill(const int* __restrict__ src, const int* __restrict__ dst, int E,
                       const int* __restrict__ off, const int* __restrict__ deg,
                       const int* __restrict__ rank, int* __restrict__ csr){
  int t = blockIdx.x * 256 + threadIdx.x;
  if (t < E){
    int d = dst[t];
    csr[off[d] + rank[t]] = src[t];
  } else if (t < E + NNODES){
    int n = t - E;
    csr[off[n] + deg[n]] = n;
  }
}

// ---------------- proj via MFMA with fused gather ----------------
__global__ __launch_bounds__(256) void k_proj_mfma(const float* __restrict__ xp,
                                                   const float* __restrict__ emb,
                                                   const unsigned short* __restrict__ Bt,
                                                   const float* __restrict__ bias,
                                                   unsigned short* __restrict__ Xb){
  __shared__ unsigned short As[64][40];
  __shared__ unsigned short Bs[128][40];
  __shared__ int ids[64];
  int tid = threadIdx.x;
  int bm = blockIdx.x * 64;
  int w = tid >> 6, lane = tid & 63;
  int wm = (w >> 1) * 32, wn = (w & 1) * 64;
  int quad = lane >> 4, l16 = lane & 15;
  if (tid < 64){
    int g = bm + tid;
    ids[tid] = (g < NNODES) ? (int)xp[(size_t)g * XP_COLS] : 0;
  }
  float4v acc[2][4];
  #pragma unroll
  for (int i = 0; i < 2; i++)
    #pragma unroll
    for (int j = 0; j < 4; j++) acc[i][j] = (float4v){0.f,0.f,0.f,0.f};
  int am = tid >> 2, ak = (tid & 3) * 8;
  int gm = bm + am;
  bool mv = gm < NNODES;
  int brow = tid >> 1, bk = (tid & 1) * 16;
  __syncthreads();

  for (int k0 = 0; k0 < 192; k0 += 32){
    float v[8];
    if (k0 < 128){
      const float* ep = emb + (size_t)ids[am] * 128 + k0 + ak;
      float4 e0 = *(const float4*)ep;
      float4 e1 = *(const float4*)(ep + 4);
      v[0]=e0.x; v[1]=e0.y; v[2]=e0.z; v[3]=e0.w;
      v[4]=e1.x; v[5]=e1.y; v[6]=e1.z; v[7]=e1.w;
    } else {
      const float* fp = xp + (size_t)gm * XP_COLS + 1 + (k0 - 128) + ak;
      #pragma unroll
      for (int i = 0; i < 8; i++) v[i] = mv ? fp[i] : 0.f;
    }
    ushort4 o0, o1;
    o0.x=f2bf(v[0]); o0.y=f2bf(v[1]); o0.z=f2bf(v[2]); o0.w=f2bf(v[3]);
    o1.x=f2bf(v[4]); o1.y=f2bf(v[5]); o1.z=f2bf(v[6]); o1.w=f2bf(v[7]);
    *(ushort4*)&As[am][ak]     = o0;
    *(ushort4*)&As[am][ak + 4] = o1;
    const unsigned short* bp = Bt + (size_t)brow * 192 + k0 + bk;
    *(uint4*)&Bs[brow][bk]     = *(const uint4*)bp;
    *(uint4*)&Bs[brow][bk + 8] = *(const uint4*)(bp + 8);
    __syncthreads();
    short8 af[2], bf[4];
    #pragma unroll
    for (int t = 0; t < 2; t++) af[t] = *(const short8*)&As[wm + t * 16 + l16][quad * 8];
    #pragma unroll
    for (int t = 0; t < 4; t++) bf[t] = *(const short8*)&Bs[wn + t * 16 + l16][quad * 8];
    #pragma unroll
    for (int tm = 0; tm < 2; tm++)
      #pragma unroll
      for (int tn = 0; tn < 4; tn++)
        acc[tm][tn] = __builtin_amdgcn_mfma_f32_16x16x32_bf16(af[tm], bf[tn], acc[tm][tn], 0, 0, 0);
    __syncthreads();
  }
  #pragma unroll
  for (int tm = 0; tm < 2; tm++){
    #pragma unroll
    for (int r = 0; r < 4; r++){
      int row = bm + wm + tm * 16 + quad * 4 + r;
      if (row >= NNODES) continue;
      #pragma unroll
      for (int tn = 0; tn < 4; tn++){
        int col = wn + tn * 16 + l16;
        float val = fmaxf(acc[tm][tn][r] + bias[col], 0.f);
        Xb[(size_t)row * 128 + col] = f2bf(val);
      }
    }
  }
}

// ---------------- MFMA GEMM with fused per-row attention dot + abs-dot bound ----------------
template<int K, int N, int MODE, int NH>
__global__ __launch_bounds__(256) void k_mfma(const unsigned short* __restrict__ A,
                                              const unsigned short* __restrict__ B0t,
                                              const unsigned short* __restrict__ B1t,
                                              void* __restrict__ C0, void* __restrict__ C1,
                                              const float* __restrict__ att,
                                              float* __restrict__ dl, float* __restrict__ dr,
                                              int* __restrict__ gmax){
  const unsigned short* Bt = blockIdx.z ? B1t : B0t;
  __shared__ unsigned short As[64][40];
  __shared__ unsigned short Bs[128][40];
  __shared__ float red[4][32];
  __shared__ float redu[4][32];
  int tid = threadIdx.x;
  int bm = blockIdx.y * 64;
  int bn = blockIdx.x * 128;
  int head = (NH == 1) ? 0 : blockIdx.x;
  int w = tid >> 6, lane = tid & 63;
  int wm = (w >> 1) * 32, wn = (w & 1) * 64;
  int quad = lane >> 4, l16 = lane & 15;
  float av[4], aav[4];
  #pragma unroll
  for (int tn = 0; tn < 4; tn++){
    av[tn] = att[head * 128 + wn + tn * 16 + l16];
    aav[tn] = fabsf(av[tn]);
  }
  float4v acc[2][4];
  #pragma unroll
  for (int i = 0; i < 2; i++)
    #pragma unroll
    for (int j = 0; j < 4; j++) acc[i][j] = (float4v){0.f,0.f,0.f,0.f};
  int am = tid >> 2, ak = (tid & 3) * 8;
  int gm = bm + am;
  bool mv = gm < NNODES;
  int brow = tid >> 1, bk = (tid & 1) * 16;

  for (int k0 = 0; k0 < K; k0 += 32){
    uint4 va = {0u,0u,0u,0u};
    if (mv) va = *(const uint4*)(A + (size_t)gm * K + k0 + ak);
    *(uint4*)&As[am][ak] = va;
    const unsigned short* bp = Bt + (size_t)(bn + brow) * K + k0 + bk;
    *(uint4*)&Bs[brow][bk]     = *(const uint4*)bp;
    *(uint4*)&Bs[brow][bk + 8] = *(const uint4*)(bp + 8);
    __syncthreads();
    short8 af[2], bf[4];
    #pragma unroll
    for (int t = 0; t < 2; t++) af[t] = *(const short8*)&As[wm + t * 16 + l16][quad * 8];
    #pragma unroll
    for (int t = 0; t < 4; t++) bf[t] = *(const short8*)&Bs[wn + t * 16 + l16][quad * 8];
    #pragma unroll
    for (int tm = 0; tm < 2; tm++)
      #pragma unroll
      for (int tn = 0; tn < 4; tn++)
        acc[tm][tn] = __builtin_amdgcn_mfma_f32_16x16x32_bf16(af[tm], bf[tn], acc[tm][tn], 0, 0, 0);
    __syncthreads();
  }
  #pragma unroll
  for (int tm = 0; tm < 2; tm++){
    #pragma unroll
    for (int r = 0; r < 4; r++){
      int row = bm + wm + tm * 16 + quad * 4 + r;
      if (row < NNODES){
        #pragma unroll
        for (int tn = 0; tn < 4; tn++){
          int col = bn + wn + tn * 16 + l16;
          float val = acc[tm][tn][r];
          if (MODE == 0 || blockIdx.z == 0){
            unsigned short* C = (unsigned short*)(blockIdx.z ? C1 : C0);
            C[(size_t)row * N + col] = f2bf(val);
          } else {
            ((float*)C1)[(size_t)row * N + col] = val;
          }
        }
      }
      float pd = acc[tm][0][r] * av[0];
      pd = fmaf(acc[tm][1][r], av[1], pd);
      pd = fmaf(acc[tm][2][r], av[2], pd);
      pd = fmaf(acc[tm][3][r], av[3], pd);
      float pu = fabsf(acc[tm][0][r]) * aav[0];
      pu = fmaf(fabsf(acc[tm][1][r]), aav[1], pu);
      pu = fmaf(fabsf(acc[tm][2][r]), aav[2], pu);
      pu = fmaf(fabsf(acc[tm][3][r]), aav[3], pu);
      pd = rowsum16(pd);
      pu = rowsum16(pu);
      if (l16 == 0){
        red[w][tm * 16 + quad * 4 + r]  = pd;
        redu[w][tm * 16 + quad * 4 + r] = pu;
      }
    }
  }
  __syncthreads();
  if (tid < 64){
    float vd, vu;
    if (tid < 32){ vd = red[0][tid] + red[1][tid];   vu = redu[0][tid] + redu[1][tid]; }
    else { vd = red[2][tid & 31] + red[3][tid & 31]; vu = redu[2][tid & 31] + redu[3][tid & 31]; }
    int row = bm + tid;
    bool ok = row < NNODES;
    if (ok){
      float* D = blockIdx.z ? dr : dl;
      D[row * NH + head] = vd;
    }
    if (blockIdx.z == 0){
      float v = ok ? fmaf(0.4f, vu, 0.6f * vd) : -4.0e6f;
      #pragma unroll
      for (int dd = 1; dd < 64; dd <<= 1) v = fmaxf(v, __shfl_xor(v, dd));
      if (tid == 0) atomicMax(&gmax[head], (int)ceilf(v * 256.0f) + (1 << 30));
    }
  }
}

// ---------------- layer-1 GATv2: block per node, round-robin 4-edge batches per wave ----------------
__global__ __launch_bounds__(256) void k_attn1(const unsigned short* __restrict__ xl,
                                               const unsigned short* __restrict__ xr,
                                               const float* __restrict__ dl, const float* __restrict__ dr,
                                               const float* __restrict__ att, const float* __restrict__ bias,
                                               const int* __restrict__ gmax,
                                               const int* __restrict__ off, const int* __restrict__ csr,
                                               unsigned short* __restrict__ out){
  int tid = threadIdx.x;
  int w = tid >> 6, lane = tid & 63;
  int n = blockIdx.x;
  int h = lane >> 4;
  uint4 ur = *(const uint4*)(xr + (size_t)n * 512 + lane * 8);
  float r[8]; unpack8(ur, r);
  const float* ap = att + lane * 8;
  float4 A0 = *(const float4*)ap, A1 = *(const float4*)(ap + 4);
  float a[8] = {A0.x,A0.y,A0.z,A0.w,A1.x,A1.y,A1.z,A1.w};
  float V = 0.f;
  #pragma unroll
  for (int i = 0; i < 8; i++) V = fmaf(fabsf(a[i]), fabsf(r[i]), V);
  V = rowsum16(V);
  float Mg = (float)(gmax[h] - (1 << 30)) * (1.0f / 256.0f);
  float base = fmaf(0.6f, dr[n * 4 + h], -Mg - 0.4f * V);
  int beg = off[n], end = off[n + 1];
  int cnt = end - beg;
  int B = (cnt + 3) >> 2;

  float s = 0.f;
  float acc[8] = {0,0,0,0,0,0,0,0};
  for (int b = w; b < B; b += 4){
    int j0 = beg + b * 4;
    int i1 = j0 + 1, i2 = j0 + 2, i3 = j0 + 3;
    float m1 = 1.f, m2 = 1.f, m3 = 1.f;
    if (i1 >= end){ i1 = j0; m1 = 0.f; }
    if (i2 >= end){ i2 = j0; m2 = 0.f; }
    if (i3 >= end){ i3 = j0; m3 = 0.f; }
    int s0 = csr[j0], s1 = csr[i1], s2 = csr[i2], s3 = csr[i3];
    uint4 u0 = *(const uint4*)(xl + (size_t)s0 * 512 + lane * 8);
    uint4 u1 = *(const uint4*)(xl + (size_t)s1 * 512 + lane * 8);
    uint4 u2 = *(const uint4*)(xl + (size_t)s2 * 512 + lane * 8);
    uint4 u3 = *(const uint4*)(xl + (size_t)s3 * 512 + lane * 8);
    float d0 = dl[s0 * 4 + h], d1 = dl[s1 * 4 + h];
    float d2 = dl[s2 * 4 + h], d3 = dl[s3 * 4 + h];
    float x0[8], x1[8], x2[8], x3[8];
    unpack8(u0, x0); unpack8(u1, x1); unpack8(u2, x2); unpack8(u3, x3);
    float p0 = 0.f, p1 = 0.f, p2 = 0.f, p3 = 0.f;
    #pragma unroll
    for (int i = 0; i < 8; i++){
      p0 = fmaf(a[i], fabsf(x0[i] + r[i]), p0);
      p1 = fmaf(a[i], fabsf(x1[i] + r[i]), p1);
      p2 = fmaf(a[i], fabsf(x2[i] + r[i]), p2);
      p3 = fmaf(a[i], fabsf(x3[i] + r[i]), p3);
    }
    p0 = rowsum16(p0); p1 = rowsum16(p1); p2 = rowsum16(p2); p3 = rowsum16(p3);
    float ex0 = __expf(fmaf(0.4f, p0, fmaf(0.6f, d0, base)));
    float ex1 = __expf(fmaf(0.4f, p1, fmaf(0.6f, d1, base))) * m1;
    float ex2 = __expf(fmaf(0.4f, p2, fmaf(0.6f, d2, base))) * m2;
    float ex3 = __expf(fmaf(0.4f, p3, fmaf(0.6f, d3, base))) * m3;
    s += (ex0 + ex1) + (ex2 + ex3);
    #pragma unroll
    for (int i = 0; i < 8; i++){
      float t = fmaf(ex0, x0[i], ex1 * x1[i]);
      t = fmaf(ex2, x2[i], t);
      acc[i] = fmaf(ex3, x3[i], acc[i] + t);
    }
  }
  __shared__ float accsh[4][512];
  __shared__ float ssh[4][4];
  *(float4*)&accsh[w][lane * 8]     = make_float4(acc[0], acc[1], acc[2], acc[3]);
  *(float4*)&accsh[w][lane * 8 + 4] = make_float4(acc[4], acc[5], acc[6], acc[7]);
  if ((lane & 15) == 0) ssh[w][h] = s;
  __syncthreads();
  for (int c = tid; c < 512; c += 256){
    float v = (accsh[0][c] + accsh[1][c]) + (accsh[2][c] + accsh[3][c]);
    int hh = c >> 7;
    float sv = (ssh[0][hh] + ssh[1][hh]) + (ssh[2][hh] + ssh[3][hh]);
    float o = v / (sv + 1e-16f) + bias[c];
    out[(size_t)n * 512 + c] = f2bf(fmaxf(o, 0.f));
  }
}

// ---------------- attn2 batch compute (4 edges, branch-free, DPP+shfl reduction) ----------------
__device__ __forceinline__ void attn2_batch(const uint32* u, const float* d,
                                            float2 rv, float2 av, float base,
                                            float& s, float& a0, float& a1){
  float x00 = bflo(u[0]), x01 = bfhi(u[0]);
  float x10 = bflo(u[1]), x11 = bfhi(u[1]);
  float x20 = bflo(u[2]), x21 = bfhi(u[2]);
  float x30 = bflo(u[3]), x31 = bfhi(u[3]);
  float p0 = fmaf(av.x, fabsf(x00 + rv.x), av.y * fabsf(x01 + rv.y));
  float p1 = fmaf(av.x, fabsf(x10 + rv.x), av.y * fabsf(x11 + rv.y));
  float p2 = fmaf(av.x, fabsf(x20 + rv.x), av.y * fabsf(x21 + rv.y));
  float p3 = fmaf(av.x, fabsf(x30 + rv.x), av.y * fabsf(x31 + rv.y));
  p0 = red64(p0); p1 = red64(p1); p2 = red64(p2); p3 = red64(p3);
  float ex0 = __expf(fmaf(0.4f, p0, fmaf(0.6f, d[0], base)));
  float ex1 = __expf(fmaf(0.4f, p1, fmaf(0.6f, d[1], base)));
  float ex2 = __expf(fmaf(0.4f, p2, fmaf(0.6f, d[2], base)));
  float ex3 = __expf(fmaf(0.4f, p3, fmaf(0.6f, d[3], base)));
  s += (ex0 + ex1) + (ex2 + ex3);
  float t0 = fmaf(ex0, x00, ex1 * x10); t0 = fmaf(ex2, x20, t0);
  float t1 = fmaf(ex0, x01, ex1 * x11); t1 = fmaf(ex2, x21, t1);
  a0 = fmaf(ex3, x30, a0 + t0);
  a1 = fmaf(ex3, x31, a1 + t1);
}

// ---------------- layer-2 GATv2 + fused output GEMM, 16 waves/block wave-per-node ----------------
__global__ __launch_bounds__(1024) void k_attn2(const unsigned short* __restrict__ xl,
                                                const float* __restrict__ xr,
                                                const float* __restrict__ dl, const float* __restrict__ dr,
                                                const float* __restrict__ att, const float* __restrict__ bias,
                                                const float* __restrict__ outW, const float* __restrict__ outb,
                                                const int* __restrict__ gmax,
                                                const int* __restrict__ off, const int* __restrict__ csr,
                                                float* __restrict__ out){
  __shared__ float Wsh[1280];
  int tid = threadIdx.x;
  for (int i = tid; i < 1280; i += 1024) Wsh[i] = outW[i];
  __syncthreads();
  int lane = tid & 63;
  int n = blockIdx.x * 16 + (tid >> 6);
  float2 rv = *(const float2*)(xr + (size_t)n * 128 + lane * 2);
  float2 av = *(const float2*)(att + lane * 2);
  float V = red64(fmaf(fabsf(av.x), fabsf(rv.x), fabsf(av.y) * fabsf(rv.y)));
  float Mg = (float)(gmax[0] - (1 << 30)) * (1.0f / 256.0f);
  float base = fmaf(0.6f, dr[n], -Mg - 0.4f * V);
  int beg = off[n], end = off[n + 1];
  int cnt = end - beg;
  int nfull = cnt >> 2;
  float s = 0.f;
  float a0 = 0.f, a1 = 0.f;
  uint32 uA[4], uB[4];
  float dA[4], dB[4];
  int j = beg;
  if (nfull > 0){
    int s0 = csr[j], s1 = csr[j+1], s2 = csr[j+2], s3 = csr[j+3];
    uA[0] = *(const uint32*)(xl + (size_t)s0 * 128 + lane * 2);
    uA[1] = *(const uint32*)(xl + (size_t)s1 * 128 + lane * 2);
    uA[2] = *(const uint32*)(xl + (size_t)s2 * 128 + lane * 2);
    uA[3] = *(const uint32*)(xl + (size_t)s3 * 128 + lane * 2);
    dA[0] = dl[s0]; dA[1] = dl[s1]; dA[2] = dl[s2]; dA[3] = dl[s3];
  }
  for (int b = 0; b < nfull; b++){
    int jn = j + 4;
    if (b + 1 < nfull){
      int s0 = csr[jn], s1 = csr[jn+1], s2 = csr[jn+2], s3 = csr[jn+3];
      uB[0] = *(const uint32*)(xl + (size_t)s0 * 128 + lane * 2);
      uB[1] = *(const uint32*)(xl + (size_t)s1 * 128 + lane * 2);
      uB[2] = *(const uint32*)(xl + (size_t)s2 * 128 + lane * 2);
      uB[3] = *(const uint32*)(xl + (size_t)s3 * 128 + lane * 2);
      dB[0] = dl[s0]; dB[1] = dl[s1]; dB[2] = dl[s2]; dB[3] = dl[s3];
    }
    attn2_batch(uA, dA, rv, av, base, s, a0, a1);
    j = jn;
    #pragma unroll
    for (int i = 0; i < 4; i++){ uA[i] = uB[i]; dA[i] = dB[i]; }
  }
  for (; j < end; j++){
    int sn = csr[j];
    float dls = dl[sn];
    uint32 u = *(const uint32*)(xl + (size_t)sn * 128 + lane * 2);
    float x0 = bflo(u), x1 = bfhi(u);
    float p = red64(fmaf(av.x, fabsf(x0 + rv.x), av.y * fabsf(x1 + rv.y)));
    float ex = __expf(fmaf(0.4f, p, fmaf(0.6f, dls, base)));
    s += ex;
    a0 = fmaf(ex, x0, a0);
    a1 = fmaf(ex, x1, a1);
  }
  float inv = 1.f / (s + 1e-16f);
  int c = lane * 2;
  float x2_0 = fmaf(a0, inv, bias[c]);
  float x2_1 = fmaf(a1, inv, bias[c + 1]);
  #pragma unroll
  for (int o = 0; o < 10; o++){
    float p = fmaf(x2_0, Wsh[c * 10 + o], x2_1 * Wsh[(c + 1) * 10 + o]);
    p = red64(p);
    if (lane == 0) out[(size_t)n * 10 + o] = p + outb[o];
  }
}

extern "C" void kernel_launch(void* const* d_in, const int* in_sizes, int n_in,
                              void* d_out, int out_size, void* d_ws, size_t ws_size,
                              hipStream_t stream){
  const float* xp    = (const float*)d_in[0];
  const int*   ei    = (const int*)  d_in[1];
  const float* emb   = (const float*)d_in[2];
  const float* projW = (const float*)d_in[3];
  const float* projb = (const float*)d_in[4];
  const float* W1l   = (const float*)d_in[5];
  const float* W1r   = (const float*)d_in[6];
  const float* att1  = (const float*)d_in[7];
  const float* b1    = (const float*)d_in[8];
  const float* W2l   = (const float*)d_in[9];
  const float* W2r   = (const float*)d_in[10];
  const float* att2  = (const float*)d_in[11];
  const float* b2    = (const float*)d_in[12];
  const float* outW  = (const float*)d_in[13];
  const float* outb  = (const float*)d_in[14];
  float* out = (float*)d_out;

  int E = in_sizes[1] / 2;
  const int* esrc = ei;
  const int* edst = ei + E;

  char* w = (char*)d_ws;
  int* gmaxi = (int*)w; w += 32;            // [0..3] layer1 heads, [4] layer2
  int* deg  = (int*)w; w += (size_t)NNODES * 4;
  int* off  = (int*)w; w += (size_t)(NNODES + 4) * 4;
  int* rank = (int*)w; w += (size_t)E * 4;
  int* csr  = (int*)w; w += (size_t)(NNODES + E) * 4;
  unsigned short* Xb   = (unsigned short*)w; w += (size_t)NNODES * 128 * 2;
  unsigned short* Wt1l = (unsigned short*)w; w += (size_t)512 * 128 * 2;
  unsigned short* Wt1r = (unsigned short*)w; w += (size_t)512 * 128 * 2;
  unsigned short* Wt2l = (unsigned short*)w; w += (size_t)128 * 512 * 2;
  unsigned short* Wt2r = (unsigned short*)w; w += (size_t)128 * 512 * 2;
  unsigned short* Wtp  = (unsigned short*)w; w += (size_t)128 * 192 * 2;
  unsigned short* xl1b = (unsigned short*)w; w += (size_t)NNODES * 512 * 2;
  unsigned short* xr1b = (unsigned short*)w; w += (size_t)NNODES * 512 * 2;
  unsigned short* X1b  = (unsigned short*)w; w += (size_t)NNODES * 512 * 2;
  unsigned short* xl2b = (unsigned short*)w; w += (size_t)NNODES * 128 * 2;
  float* xr2 = (float*)w; w += (size_t)NNODES * 128 * 4;
  float* dl1 = (float*)w; w += (size_t)NNODES * 4 * 4;
  float* dr1 = (float*)w; w += (size_t)NNODES * 4 * 4;
  float* dl2 = (float*)w; w += (size_t)NNODES * 4;
  float* dr2 = (float*)w; w += (size_t)NNODES * 4;

  hipMemsetAsync(gmaxi, 0, 32 + (size_t)NNODES * 4, stream);  // covers gmaxi + deg
  int CB = (E + 255) / 256;
  k_cvt_count<<<CB + 280, 256, 0, stream>>>(
      edst, E, CB, deg, rank, W1l, W1r, W2l, W2r, projW, Wt1l, Wt1r, Wt2l, Wt2r, Wtp);
  k_scan<<<1, 256, 0, stream>>>(deg, off);
  k_fill<<<(E + NNODES + 255) / 256, 256, 0, stream>>>(esrc, edst, E, off, deg, rank, csr);

  k_proj_mfma<<<dim3((NNODES + 63) / 64), 256, 0, stream>>>(xp, emb, Wtp, projb, Xb);
  k_mfma<128, 512, 0, 4><<<dim3(4, (NNODES + 63) / 64, 2), 256, 0, stream>>>(
      Xb, Wt1l, Wt1r, xl1b, xr1b, att1, dl1, dr1, gmaxi);
  k_attn1<<<NNODES, 256, 0, stream>>>(xl1b, xr1b, dl1, dr1, att1, b1, gmaxi, off, csr, X1b);
  k_mfma<512, 128, 1, 1><<<dim3(1, (NNODES + 63) / 64, 2), 256, 0, stream>>>(
      X1b, Wt2l, Wt2r, xl2b, xr2, att2, dl2, dr2, gmaxi + 4);
  k_attn2<<<NNODES / 16, 1024, 0, stream>>>(xl2b, xr2, dl2, dr2, att2, b2, outW, outb, gmaxi + 4, off, csr, out);
}